// Round 8
// baseline (808.590 us; speedup 1.0000x reference)
//
#include <hip/hip_runtime.h>
#include <hip/hip_fp16.h>

// GCN 2-layer, N=100000, F=64, H=128, O=100, out [N,1] fp32.
// out = agg(relu(agg(x)@W1 + b1) . (W2@Wl)) + (b2@Wl + bl)
// agg via CSR-by-dst GATHER; layer-1 GEMV via MFMA (fp16 hi+lo split W1).
// CSR built with a two-pass bucketed scatter (no 16x write amplification).

#define N_NODES 100000
#define F_IN 64
#define HID 128
#define OUT2 100
#define SCAN_CHUNK 1024
#define BSHIFT 8
#define BNODES 256
#define NBUCKETS ((N_NODES + BNODES - 1) / BNODES)  // 391
#define BCAP 9216  // LDS staging cap per bucket (mean 4096, sigma 64)

typedef _Float16 half8 __attribute__((ext_vector_type(8)));
typedef float f32x4 __attribute__((ext_vector_type(4)));

static __device__ __forceinline__ half8 as_half8(uint4 u) {
    union { uint4 u; half8 h; } x; x.u = u; return x.h;
}

__global__ void hist_kernel(const int* __restrict__ dst, int* __restrict__ cnt, int E) {
    int e = blockIdx.x * blockDim.x + threadIdx.x;
    if (e < E) atomicAdd(&cnt[dst[e]], 1);
}

// Block-level exclusive scan over cnt (SCAN_CHUNK/block) + fused dinv compute.
__global__ __launch_bounds__(256) void scan1_kernel(const int* __restrict__ cnt,
                                                    int* __restrict__ row_ptr,
                                                    int* __restrict__ bsum,
                                                    float* __restrict__ dinv, int n) {
    __shared__ int lsum[256];
    int t = threadIdx.x;
    int i0 = blockIdx.x * SCAN_CHUNK + t * 4;
    int a = 0, b = 0, c = 0, d = 0;
    if (i0 < n)     a = cnt[i0];
    if (i0 + 1 < n) b = cnt[i0 + 1];
    if (i0 + 2 < n) c = cnt[i0 + 2];
    if (i0 + 3 < n) d = cnt[i0 + 3];
    if (i0 < n)     dinv[i0]     = rsqrtf((float)a + 1.0f);
    if (i0 + 1 < n) dinv[i0 + 1] = rsqrtf((float)b + 1.0f);
    if (i0 + 2 < n) dinv[i0 + 2] = rsqrtf((float)c + 1.0f);
    if (i0 + 3 < n) dinv[i0 + 3] = rsqrtf((float)d + 1.0f);
    int tsum = a + b + c + d;
    lsum[t] = tsum;
    __syncthreads();
    for (int off = 1; off < 256; off <<= 1) {
        int val = (t >= off) ? lsum[t - off] : 0;
        __syncthreads();
        lsum[t] += val;
        __syncthreads();
    }
    int excl = lsum[t] - tsum;
    if (i0 < n)     row_ptr[i0]     = excl;
    if (i0 + 1 < n) row_ptr[i0 + 1] = excl + a;
    if (i0 + 2 < n) row_ptr[i0 + 2] = excl + a + b;
    if (i0 + 3 < n) row_ptr[i0 + 3] = excl + a + b + c;
    if (t == 255) bsum[blockIdx.x] = lsum[255];
}

// Block 0: bsum scan (wave 0) + v = W2@Wl (threads 64..191) + c (thread 192).
// Blocks 1..8: pack W1 into MFMA B-fragment layout, fp16 hi+lo split.
// Blocks >=9: y = fp16(dinv .* x).
__global__ __launch_bounds__(256) void prep_kernel(
    int* __restrict__ bsum, int nb,
    const float* __restrict__ W1, const float* __restrict__ W2,
    const float* __restrict__ b2, const float* __restrict__ Wl,
    const float* __restrict__ bl,
    float* __restrict__ v, float* __restrict__ c,
    uint4* __restrict__ Wpk,
    const float4* __restrict__ x4, __half2* __restrict__ y2,
    const float* __restrict__ dinv, int n16) {
    int t = threadIdx.x;
    if (blockIdx.x == 0) {
        if (t < 64) {
            int i0 = 2 * t;
            int a = (i0 < nb) ? bsum[i0] : 0;
            int b = (i0 + 1 < nb) ? bsum[i0 + 1] : 0;
            int s = a + b;
            int inc = s;
            #pragma unroll
            for (int off = 1; off < 64; off <<= 1) {
                int u = __shfl_up(inc, off, 64);
                if (t >= off) inc += u;
            }
            int excl = inc - s;
            if (i0 < nb)     bsum[i0]     = excl;
            if (i0 + 1 < nb) bsum[i0 + 1] = excl + a;
        } else if (t < 192) {
            int j = t - 64;  // < 128
            float acc = 0.f;
            for (int k = 0; k < OUT2; ++k) acc += W2[j * OUT2 + k] * Wl[k];
            v[j] = acc;
        } else if (t == 192) {
            float acc = bl[0];
            for (int k = 0; k < OUT2; ++k) acc += b2[k] * Wl[k];
            *c = acc;
        }
    } else if (blockIdx.x <= 8) {
        // idx in [0,2048): bit10 = part (0=hi,1=lo), bits9..7 = cb, bit6 = kf, bits5..0 = lane
        int idx = (blockIdx.x - 1) * 256 + t;
        int lane2 = idx & 63;
        int kf    = (idx >> 6) & 1;
        int cb    = (idx >> 7) & 7;
        int part  = (idx >> 10) & 1;
        union { uint4 u; unsigned short s[8]; } pk;
        #pragma unroll
        for (int j = 0; j < 8; ++j) {
            int k    = kf * 32 + (lane2 >> 4) * 8 + j;
            int colg = cb * 16 + (lane2 & 15);
            float w = W1[k * HID + colg];
            __half h = __float2half_rn(w);
            if (part) h = __float2half_rn(w - __half2float(h));
            pk.s[j] = __half_as_ushort(h);
        }
        Wpk[idx] = pk.u;
    } else {
        int i = (blockIdx.x - 9) * 256 + t;
        if (i < n16) {
            float di = dinv[i >> 4];
            float4 xv = x4[i];
            y2[2 * i]     = __floats2half2_rn(xv.x * di, xv.y * di);
            y2[2 * i + 1] = __floats2half2_rn(xv.z * di, xv.w * di);
        }
    }
}

// Finalize row_ptr with block offsets; init per-bucket cursors from row_ptr.
__global__ void scan3_kernel(int* __restrict__ row_ptr, const int* __restrict__ bsum,
                             int* __restrict__ bcur, int n, int E) {
    int i = blockIdx.x * blockDim.x + threadIdx.x;
    if (i < n) {
        int r = row_ptr[i] + bsum[i / SCAN_CHUNK];
        row_ptr[i] = r;
        if ((i & (BNODES - 1)) == 0) bcur[i >> BSHIFT] = r;
    }
    if (i == 0) row_ptr[n] = E;
}

// Pass A: partition edges into dst-buckets (256 nodes each), packed 4 B/edge:
// entry = (src<<8) | (dst&255). Bucket regions coincide with csr row ranges,
// so ebuf shares csr's memory. 391 sequential write streams -> low amplification.
__global__ void partA_kernel(const int* __restrict__ src, const int* __restrict__ dst,
                             int* __restrict__ bcur, unsigned int* __restrict__ ebuf, int E) {
    int e = blockIdx.x * blockDim.x + threadIdx.x;
    if (e < E) {
        int s = src[e], d = dst[e];
        int pos = atomicAdd(&bcur[d >> BSHIFT], 1);
        ebuf[pos] = ((unsigned int)s << 8) | (unsigned int)(d & (BNODES - 1));
    }
}

// Pass B: one block per bucket, in-place within the bucket's csr range.
// Read whole range into registers, sync, scatter via LDS cursors into LDS
// staging, sync, stream back coalesced. csr[pos] = src afterwards.
__global__ __launch_bounds__(256) void partB_kernel(
    const int* __restrict__ row_ptr, unsigned int* __restrict__ csr, int n) {
    __shared__ int lcur[BNODES];
    __shared__ unsigned int sbuf[BCAP];
    int b = blockIdx.x;
    int t = threadIdx.x;
    int node0 = b << BSHIFT;
    int nlocal = min(BNODES, n - node0);
    int base = row_ptr[node0];
    int endp = row_ptr[node0 + nlocal];
    int cnt = endp - base;
    if (t < nlocal) lcur[t] = row_ptr[node0 + t] - base;
    else if (t < BNODES) lcur[t] = 0;
    unsigned int ebuf_reg[BCAP / 256];
    #pragma unroll
    for (int k = 0; k < BCAP / 256; ++k) {
        int idx = k * 256 + t;
        ebuf_reg[k] = (idx < cnt) ? csr[base + idx] : 0xFFFFFFFFu;
    }
    __syncthreads();  // all reads of the range complete
    #pragma unroll
    for (int k = 0; k < BCAP / 256; ++k) {
        unsigned int e = ebuf_reg[k];
        if (e != 0xFFFFFFFFu) {
            int dl = (int)(e & (BNODES - 1));
            int p = atomicAdd(&lcur[dl], 1);
            sbuf[p] = e >> 8;
        }
    }
    __syncthreads();
    for (int idx = t; idx < cnt; idx += 256) csr[base + idx] = sbuf[idx];
}

// Fused layer 1: block = 4 waves = 16 nodes (one MFMA tile).
__global__ __launch_bounds__(256) void fused1_kernel(
    const uint4* __restrict__ y, const float4* __restrict__ x4,
    const int* __restrict__ row_ptr, const int* __restrict__ csr,
    const float* __restrict__ dinv, const uint4* __restrict__ Wpk,
    const float* __restrict__ b1, const float* __restrict__ v,
    float* __restrict__ zz, int n) {
    __shared__ uint4 Atile[16 * 9];
    int t = threadIdx.x;
    int lane = t & 63;
    int wave = t >> 6;
    int node0 = blockIdx.x * 16;
    int q = lane >> 3, col = lane & 7;

    #pragma unroll
    for (int j = 0; j < 4; ++j) {
        int m = wave * 4 + j;
        int node = node0 + m;
        float f[8];
        #pragma unroll
        for (int r = 0; r < 8; ++r) f[r] = 0.f;
        int beg = row_ptr[node], end = row_ptr[node + 1];
        if (y) {
            if (q == 0) {
                uint4 u = y[node * 8 + col];
                const __half2* hp = (const __half2*)&u;
                #pragma unroll
                for (int r = 0; r < 4; ++r) {
                    float2 fv = __half22float2(hp[r]);
                    f[2 * r] = fv.x; f[2 * r + 1] = fv.y;
                }
            }
            int p = beg + q;
            int s0 = (p < end) ? csr[p] : -1;
            int s1 = (p + 8 < end) ? csr[p + 8] : -1;
            for (int cb = beg; cb < end; cb += 16) {
                int c0 = s0, c1 = s1;
                int np = cb + 16 + q;
                s0 = (np < end) ? csr[np] : -1;
                s1 = (np + 8 < end) ? csr[np + 8] : -1;
                uint4 u0, u1;
                if (c0 >= 0) u0 = y[c0 * 8 + col];
                if (c1 >= 0) u1 = y[c1 * 8 + col];
                if (c0 >= 0) {
                    const __half2* hp = (const __half2*)&u0;
                    #pragma unroll
                    for (int r = 0; r < 4; ++r) {
                        float2 fv = __half22float2(hp[r]);
                        f[2 * r] += fv.x; f[2 * r + 1] += fv.y;
                    }
                }
                if (c1 >= 0) {
                    const __half2* hp = (const __half2*)&u1;
                    #pragma unroll
                    for (int r = 0; r < 4; ++r) {
                        float2 fv = __half22float2(hp[r]);
                        f[2 * r] += fv.x; f[2 * r + 1] += fv.y;
                    }
                }
            }
        } else {
            if (q == 0) {
                float di0 = dinv[node];
                float4 a = x4[node * 16 + 2 * col];
                float4 b = x4[node * 16 + 2 * col + 1];
                f[0] = di0 * a.x; f[1] = di0 * a.y; f[2] = di0 * a.z; f[3] = di0 * a.w;
                f[4] = di0 * b.x; f[5] = di0 * b.y; f[6] = di0 * b.z; f[7] = di0 * b.w;
            }
            int p = beg + q;
            int s0 = (p < end) ? csr[p] : -1;
            int s1 = (p + 8 < end) ? csr[p + 8] : -1;
            for (int cb = beg; cb < end; cb += 16) {
                int c0 = s0, c1 = s1;
                int np = cb + 16 + q;
                s0 = (np < end) ? csr[np] : -1;
                s1 = (np + 8 < end) ? csr[np + 8] : -1;
                if (c0 >= 0) {
                    float w = dinv[c0];
                    float4 a = x4[c0 * 16 + 2 * col];
                    float4 b = x4[c0 * 16 + 2 * col + 1];
                    f[0] += w * a.x; f[1] += w * a.y; f[2] += w * a.z; f[3] += w * a.w;
                    f[4] += w * b.x; f[5] += w * b.y; f[6] += w * b.z; f[7] += w * b.w;
                }
                if (c1 >= 0) {
                    float w = dinv[c1];
                    float4 a = x4[c1 * 16 + 2 * col];
                    float4 b = x4[c1 * 16 + 2 * col + 1];
                    f[0] += w * a.x; f[1] += w * a.y; f[2] += w * a.z; f[3] += w * a.w;
                    f[4] += w * b.x; f[5] += w * b.y; f[6] += w * b.z; f[7] += w * b.w;
                }
            }
        }
        #pragma unroll
        for (int off = 8; off < 64; off <<= 1) {
            #pragma unroll
            for (int r = 0; r < 8; ++r) f[r] += __shfl_xor(f[r], off, 64);
        }
        if (lane < 8) {
            float di = dinv[node];
            union { uint4 u; __half2 h[4]; } pk;
            #pragma unroll
            for (int r = 0; r < 4; ++r)
                pk.h[r] = __floats2half2_rn(di * f[2 * r], di * f[2 * r + 1]);
            Atile[m * 9 + lane] = pk.u;
        }
    }
    __syncthreads();
    if (t >= 64) return;

    int mm = lane & 15, kq = lane >> 4;
    half8 A0 = as_half8(Atile[mm * 9 + kq]);
    half8 A1 = as_half8(Atile[mm * 9 + 4 + kq]);
    f32x4 acc[8];
    #pragma unroll
    for (int cb = 0; cb < 8; ++cb) acc[cb] = (f32x4){0.f, 0.f, 0.f, 0.f};
    #pragma unroll
    for (int cb = 0; cb < 8; ++cb) {
        half8 bh0 = as_half8(Wpk[(cb * 2 + 0) * 64 + lane]);
        half8 bh1 = as_half8(Wpk[(cb * 2 + 1) * 64 + lane]);
        half8 bl0 = as_half8(Wpk[1024 + (cb * 2 + 0) * 64 + lane]);
        half8 bl1 = as_half8(Wpk[1024 + (cb * 2 + 1) * 64 + lane]);
        acc[cb] = __builtin_amdgcn_mfma_f32_16x16x32_f16(A0, bh0, acc[cb], 0, 0, 0);
        acc[cb] = __builtin_amdgcn_mfma_f32_16x16x32_f16(A1, bh1, acc[cb], 0, 0, 0);
        acc[cb] = __builtin_amdgcn_mfma_f32_16x16x32_f16(A0, bl0, acc[cb], 0, 0, 0);
        acc[cb] = __builtin_amdgcn_mfma_f32_16x16x32_f16(A1, bl1, acc[cb], 0, 0, 0);
    }
    float zp[4] = {0.f, 0.f, 0.f, 0.f};
    #pragma unroll
    for (int cb = 0; cb < 8; ++cb) {
        int colg = cb * 16 + mm;
        float bb = b1[colg], vv = v[colg];
        #pragma unroll
        for (int r = 0; r < 4; ++r) {
            float h = acc[cb][r] + bb;
            h = fmaxf(h, 0.f);
            zp[r] += h * vv;
        }
    }
    #pragma unroll
    for (int off = 1; off < 16; off <<= 1) {
        #pragma unroll
        for (int r = 0; r < 4; ++r) zp[r] += __shfl_xor(zp[r], off, 64);
    }
    if (mm == 0) {
        int nb = node0 + kq * 4;
        #pragma unroll
        for (int r = 0; r < 4; ++r) zz[nb + r] = dinv[nb + r] * zp[r];
    }
}

// Layer 2 (collapsed): out[i] = c + dinv[i]*(zz[i] + sum_in zz[s]). 16 lanes/node.
__global__ void out_kernel(const int* __restrict__ row_ptr, const int* __restrict__ csr,
                           const float* __restrict__ dinv, const float* __restrict__ zz,
                           const float* __restrict__ c, float* __restrict__ out, int n) {
    int tid = blockIdx.x * blockDim.x + threadIdx.x;
    int node = tid >> 4;
    int sub = tid & 15;
    if (node >= n) return;
    int beg = row_ptr[node], end = row_ptr[node + 1];
    float acc = 0.f;
    for (int e = beg + sub; e < end; e += 16) acc += zz[csr[e]];
    acc += __shfl_xor(acc, 1, 64);
    acc += __shfl_xor(acc, 2, 64);
    acc += __shfl_xor(acc, 4, 64);
    acc += __shfl_xor(acc, 8, 64);
    if (sub == 0) out[node] = c[0] + dinv[node] * (acc + zz[node]);
}

extern "C" void kernel_launch(void* const* d_in, const int* in_sizes, int n_in,
                              void* d_out, int out_size, void* d_ws, size_t ws_size,
                              hipStream_t stream) {
    const float* x  = (const float*)d_in[0];
    const int*   ei = (const int*)d_in[1];
    const float* W1 = (const float*)d_in[2];
    const float* b1 = (const float*)d_in[3];
    const float* W2 = (const float*)d_in[4];
    const float* b2 = (const float*)d_in[5];
    const float* Wl = (const float*)d_in[6];
    const float* bl = (const float*)d_in[7];
    float* out = (float*)d_out;

    int E = in_sizes[1] / 2;
    const int* src = ei;
    const int* dst = ei + E;

    float* ws      = (float*)d_ws;
    float* dinv    = ws;                       // N
    int*   row_ptr = (int*)(ws + N_NODES);     // N+4
    int*   cnt     = row_ptr + N_NODES + 4;    // N
    int*   bsum    = cnt + N_NODES;            // 128
    float* zz      = (float*)(bsum + 128);     // N
    float* v       = zz + N_NODES;             // 128
    float* c       = v + HID;                  // 4
    int*   bcur    = (int*)(c + 4);            // 512 (NBUCKETS=391 padded)
    int*   csr     = bcur + 512;               // E
    float* after   = (float*)(csr + E);
    uint4* Wpk     = (uint4*)after;            // 2048 uint4 (32 KB)
    __half* y      = (__half*)(after + 8192);  // N*64 halves

    size_t base_floats = (size_t)N_NODES * 3 + 4 + 128 + 128 + 4 + 512 + (size_t)E + 8192;
    size_t need_f16 = (base_floats + (size_t)N_NODES * 32) * 4;
    bool use_f16 = (ws_size >= need_f16);
    int n16 = use_f16 ? N_NODES * 16 : 0;

    int nscan = (N_NODES + SCAN_CHUNK - 1) / SCAN_CHUNK;  // 98
    int prep_blocks = 9 + (n16 + 255) / 256;

    hipMemsetAsync(cnt, 0, sizeof(int) * N_NODES, stream);
    hist_kernel<<<(E + 255) / 256, 256, 0, stream>>>(dst, cnt, E);
    scan1_kernel<<<nscan, 256, 0, stream>>>(cnt, row_ptr, bsum, dinv, N_NODES);
    prep_kernel<<<prep_blocks, 256, 0, stream>>>(
        bsum, nscan, W1, W2, b2, Wl, bl, v, c, Wpk,
        (const float4*)x, (__half2*)y, dinv, n16);
    scan3_kernel<<<(N_NODES + 255) / 256, 256, 0, stream>>>(row_ptr, bsum, bcur, N_NODES, E);
    partA_kernel<<<(E + 255) / 256, 256, 0, stream>>>(src, dst, bcur, (unsigned int*)csr, E);
    partB_kernel<<<NBUCKETS, 256, 0, stream>>>(row_ptr, (unsigned int*)csr, N_NODES);
    fused1_kernel<<<N_NODES / 16, 256, 0, stream>>>(
        use_f16 ? (const uint4*)y : nullptr, (const float4*)x,
        row_ptr, csr, dinv, Wpk, b1, v, zz, N_NODES);
    out_kernel<<<(N_NODES * 16 + 255) / 256, 256, 0, stream>>>(
        row_ptr, csr, dinv, zz, c, out, N_NODES);
}

// Round 9
// 273.811 us; speedup vs baseline: 2.9531x; 2.9531x over previous
//
#include <hip/hip_runtime.h>
#include <hip/hip_fp16.h>

// GCN 2-layer, N=100000, F=64, H=128, O=100, out [N,1] fp32.
// out = agg(relu(agg(x)@W1 + b1) . (W2@Wl)) + (b2@Wl + bl)
// agg via CSR-by-dst GATHER; layer-1 GEMV via MFMA (fp16 hi+lo split W1).
// CSR built bucket-wise: partA = LDS multi-split (1 reserve-atomic per
// bucket per block), partB = in-bucket LDS counting sort.

#define N_NODES 100000
#define F_IN 64
#define HID 128
#define OUT2 100
#define SCAN_CHUNK 1024
#define BSHIFT 8
#define BNODES 256
#define NBUCKETS ((N_NODES + BNODES - 1) / BNODES)  // 391
#define BCAP 9216   // partB LDS staging cap (bucket mean 4096, sigma ~64)
#define ACHUNK 4096 // partA edges per block
#define NB_PAD 512
#define SENTB 0xFFFFu

typedef _Float16 half8 __attribute__((ext_vector_type(8)));
typedef float f32x4 __attribute__((ext_vector_type(4)));

static __device__ __forceinline__ half8 as_half8(uint4 u) {
    union { uint4 u; half8 h; } x; x.u = u; return x.h;
}

__global__ void hist_kernel(const int* __restrict__ dst, int* __restrict__ cnt, int E) {
    int e = blockIdx.x * blockDim.x + threadIdx.x;
    if (e < E) atomicAdd(&cnt[dst[e]], 1);
}

// Block-level exclusive scan over cnt (SCAN_CHUNK/block) + fused dinv compute.
__global__ __launch_bounds__(256) void scan1_kernel(const int* __restrict__ cnt,
                                                    int* __restrict__ row_ptr,
                                                    int* __restrict__ bsum,
                                                    float* __restrict__ dinv, int n) {
    __shared__ int lsum[256];
    int t = threadIdx.x;
    int i0 = blockIdx.x * SCAN_CHUNK + t * 4;
    int a = 0, b = 0, c = 0, d = 0;
    if (i0 < n)     a = cnt[i0];
    if (i0 + 1 < n) b = cnt[i0 + 1];
    if (i0 + 2 < n) c = cnt[i0 + 2];
    if (i0 + 3 < n) d = cnt[i0 + 3];
    if (i0 < n)     dinv[i0]     = rsqrtf((float)a + 1.0f);
    if (i0 + 1 < n) dinv[i0 + 1] = rsqrtf((float)b + 1.0f);
    if (i0 + 2 < n) dinv[i0 + 2] = rsqrtf((float)c + 1.0f);
    if (i0 + 3 < n) dinv[i0 + 3] = rsqrtf((float)d + 1.0f);
    int tsum = a + b + c + d;
    lsum[t] = tsum;
    __syncthreads();
    for (int off = 1; off < 256; off <<= 1) {
        int val = (t >= off) ? lsum[t - off] : 0;
        __syncthreads();
        lsum[t] += val;
        __syncthreads();
    }
    int excl = lsum[t] - tsum;
    if (i0 < n)     row_ptr[i0]     = excl;
    if (i0 + 1 < n) row_ptr[i0 + 1] = excl + a;
    if (i0 + 2 < n) row_ptr[i0 + 2] = excl + a + b;
    if (i0 + 3 < n) row_ptr[i0 + 3] = excl + a + b + c;
    if (t == 255) bsum[blockIdx.x] = lsum[255];
}

// Block 0: bsum scan (wave 0) + v = W2@Wl (threads 64..191) + c (thread 192).
// Blocks 1..8: pack W1 into MFMA B-fragment layout, fp16 hi+lo split.
// Blocks >=9: y = fp16(dinv .* x).
__global__ __launch_bounds__(256) void prep_kernel(
    int* __restrict__ bsum, int nb,
    const float* __restrict__ W1, const float* __restrict__ W2,
    const float* __restrict__ b2, const float* __restrict__ Wl,
    const float* __restrict__ bl,
    float* __restrict__ v, float* __restrict__ c,
    uint4* __restrict__ Wpk,
    const float4* __restrict__ x4, __half2* __restrict__ y2,
    const float* __restrict__ dinv, int n16) {
    int t = threadIdx.x;
    if (blockIdx.x == 0) {
        if (t < 64) {
            int i0 = 2 * t;
            int a = (i0 < nb) ? bsum[i0] : 0;
            int b = (i0 + 1 < nb) ? bsum[i0 + 1] : 0;
            int s = a + b;
            int inc = s;
            #pragma unroll
            for (int off = 1; off < 64; off <<= 1) {
                int u = __shfl_up(inc, off, 64);
                if (t >= off) inc += u;
            }
            int excl = inc - s;
            if (i0 < nb)     bsum[i0]     = excl;
            if (i0 + 1 < nb) bsum[i0 + 1] = excl + a;
        } else if (t < 192) {
            int j = t - 64;  // < 128
            float acc = 0.f;
            for (int k = 0; k < OUT2; ++k) acc += W2[j * OUT2 + k] * Wl[k];
            v[j] = acc;
        } else if (t == 192) {
            float acc = bl[0];
            for (int k = 0; k < OUT2; ++k) acc += b2[k] * Wl[k];
            *c = acc;
        }
    } else if (blockIdx.x <= 8) {
        int idx = (blockIdx.x - 1) * 256 + t;
        int lane2 = idx & 63;
        int kf    = (idx >> 6) & 1;
        int cb    = (idx >> 7) & 7;
        int part  = (idx >> 10) & 1;
        union { uint4 u; unsigned short s[8]; } pk;
        #pragma unroll
        for (int j = 0; j < 8; ++j) {
            int k    = kf * 32 + (lane2 >> 4) * 8 + j;
            int colg = cb * 16 + (lane2 & 15);
            float w = W1[k * HID + colg];
            __half h = __float2half_rn(w);
            if (part) h = __float2half_rn(w - __half2float(h));
            pk.s[j] = __half_as_ushort(h);
        }
        Wpk[idx] = pk.u;
    } else {
        int i = (blockIdx.x - 9) * 256 + t;
        if (i < n16) {
            float di = dinv[i >> 4];
            float4 xv = x4[i];
            y2[2 * i]     = __floats2half2_rn(xv.x * di, xv.y * di);
            y2[2 * i + 1] = __floats2half2_rn(xv.z * di, xv.w * di);
        }
    }
}

// Finalize row_ptr with block offsets; init per-bucket cursors from row_ptr.
__global__ void scan3_kernel(int* __restrict__ row_ptr, const int* __restrict__ bsum,
                             int* __restrict__ bcur, int n, int E) {
    int i = blockIdx.x * blockDim.x + threadIdx.x;
    if (i < n) {
        int r = row_ptr[i] + bsum[i / SCAN_CHUNK];
        row_ptr[i] = r;
        if ((i & (BNODES - 1)) == 0) bcur[i >> BSHIFT] = r;
    }
    if (i == 0) row_ptr[n] = E;
}

// Pass A: LDS multi-split into dst-buckets. Each block handles 4096 edges:
// LDS hist over 391 buckets -> LDS scan -> ONE global reserve-atomic per
// bucket per block -> LDS-staged reorder -> coalesced flush (runs of ~10).
// Packed entry = (src<<8) | (dst&255). Bucket regions = csr row ranges.
__global__ __launch_bounds__(256) void partA_kernel(
    const int* __restrict__ src, const int* __restrict__ dst,
    int* __restrict__ bcur, unsigned int* __restrict__ ebuf, int E) {
    __shared__ unsigned int stage[ACHUNK];       // 16 KB
    __shared__ unsigned short sb[ACHUNK];        // 8 KB
    __shared__ int hist[NB_PAD];                 // counts -> inclusive scan
    __shared__ int ocnt[NB_PAD];
    __shared__ int gbase[NB_PAD];
    __shared__ int cnt2[NB_PAD];
    int t = threadIdx.x;
    int base = blockIdx.x * ACHUNK;
    int total = E - base; if (total > ACHUNK) total = ACHUNK;

    hist[t] = 0; hist[t + 256] = 0;
    cnt2[t] = 0; cnt2[t + 256] = 0;
    __syncthreads();

    unsigned int pe[16];
    unsigned short bk[16];
    #pragma unroll
    for (int k = 0; k < 16; ++k) {
        int e = base + k * 256 + t;
        if (e < E) {
            int s = src[e], d = dst[e];
            pe[k] = ((unsigned int)s << 8) | (unsigned int)(d & (BNODES - 1));
            bk[k] = (unsigned short)(d >> BSHIFT);
            atomicAdd(&hist[bk[k]], 1);
        } else {
            bk[k] = SENTB;
        }
    }
    __syncthreads();
    ocnt[t] = hist[t]; ocnt[t + 256] = hist[t + 256];
    __syncthreads();
    // inclusive Hillis-Steele scan over 512 (2 elems/thread)
    for (int off = 1; off < NB_PAD; off <<= 1) {
        int v0 = (t >= off) ? hist[t - off] : 0;
        int v1 = hist[t + 256 - off];
        __syncthreads();
        hist[t] += v0; hist[t + 256] += v1;
        __syncthreads();
    }
    // reserve global space: one atomic per non-empty bucket (rotated for stagger)
    #pragma unroll
    for (int i = 0; i < 2; ++i) {
        int b = (t + i * 256 + blockIdx.x * 131) & (NB_PAD - 1);
        int cc = ocnt[b];
        if (cc > 0 && b < NBUCKETS) gbase[b] = atomicAdd(&bcur[b], cc);
    }
    __syncthreads();
    // stage ordered by bucket
    #pragma unroll
    for (int k = 0; k < 16; ++k) {
        if (bk[k] != SENTB) {
            int b = bk[k];
            int pos = (hist[b] - ocnt[b]) + atomicAdd(&cnt2[b], 1);
            stage[pos] = pe[k];
            sb[pos] = (unsigned short)b;
        }
    }
    __syncthreads();
    // flush: consecutive idx -> same-bucket runs -> coalesced global writes
    #pragma unroll
    for (int k = 0; k < 16; ++k) {
        int idx = k * 256 + t;
        if (idx < total) {
            int b = sb[idx];
            int lo = hist[b] - ocnt[b];
            ebuf[gbase[b] + (idx - lo)] = stage[idx];
        }
    }
}

// Pass B: one block per bucket, in-place within the bucket's csr range.
__global__ __launch_bounds__(256) void partB_kernel(
    const int* __restrict__ row_ptr, unsigned int* __restrict__ csr, int n) {
    __shared__ int lcur[BNODES];
    __shared__ unsigned int sbuf[BCAP];
    int b = blockIdx.x;
    int t = threadIdx.x;
    int node0 = b << BSHIFT;
    int nlocal = min(BNODES, n - node0);
    int base = row_ptr[node0];
    int endp = row_ptr[node0 + nlocal];
    int cnt = endp - base;
    if (t < nlocal) lcur[t] = row_ptr[node0 + t] - base;
    else if (t < BNODES) lcur[t] = 0;
    unsigned int ebuf_reg[BCAP / 256];
    #pragma unroll
    for (int k = 0; k < BCAP / 256; ++k) {
        int idx = k * 256 + t;
        ebuf_reg[k] = (idx < cnt) ? csr[base + idx] : 0xFFFFFFFFu;
    }
    __syncthreads();  // all reads of the range complete
    #pragma unroll
    for (int k = 0; k < BCAP / 256; ++k) {
        unsigned int e = ebuf_reg[k];
        if (e != 0xFFFFFFFFu) {
            int dl = (int)(e & (BNODES - 1));
            int p = atomicAdd(&lcur[dl], 1);
            sbuf[p] = e >> 8;
        }
    }
    __syncthreads();
    for (int idx = t; idx < cnt; idx += 256) csr[base + idx] = sbuf[idx];
}

// Fused layer 1: block = 4 waves = 16 nodes (one MFMA tile).
__global__ __launch_bounds__(256) void fused1_kernel(
    const uint4* __restrict__ y, const float4* __restrict__ x4,
    const int* __restrict__ row_ptr, const int* __restrict__ csr,
    const float* __restrict__ dinv, const uint4* __restrict__ Wpk,
    const float* __restrict__ b1, const float* __restrict__ v,
    float* __restrict__ zz, int n) {
    __shared__ uint4 Atile[16 * 9];
    int t = threadIdx.x;
    int lane = t & 63;
    int wave = t >> 6;
    int node0 = blockIdx.x * 16;
    int q = lane >> 3, col = lane & 7;

    #pragma unroll
    for (int j = 0; j < 4; ++j) {
        int m = wave * 4 + j;
        int node = node0 + m;
        float f[8];
        #pragma unroll
        for (int r = 0; r < 8; ++r) f[r] = 0.f;
        int beg = row_ptr[node], end = row_ptr[node + 1];
        if (y) {
            if (q == 0) {
                uint4 u = y[node * 8 + col];
                const __half2* hp = (const __half2*)&u;
                #pragma unroll
                for (int r = 0; r < 4; ++r) {
                    float2 fv = __half22float2(hp[r]);
                    f[2 * r] = fv.x; f[2 * r + 1] = fv.y;
                }
            }
            int p = beg + q;
            int s0 = (p < end) ? csr[p] : -1;
            int s1 = (p + 8 < end) ? csr[p + 8] : -1;
            for (int cb = beg; cb < end; cb += 16) {
                int c0 = s0, c1 = s1;
                int np = cb + 16 + q;
                s0 = (np < end) ? csr[np] : -1;
                s1 = (np + 8 < end) ? csr[np + 8] : -1;
                uint4 u0, u1;
                if (c0 >= 0) u0 = y[c0 * 8 + col];
                if (c1 >= 0) u1 = y[c1 * 8 + col];
                if (c0 >= 0) {
                    const __half2* hp = (const __half2*)&u0;
                    #pragma unroll
                    for (int r = 0; r < 4; ++r) {
                        float2 fv = __half22float2(hp[r]);
                        f[2 * r] += fv.x; f[2 * r + 1] += fv.y;
                    }
                }
                if (c1 >= 0) {
                    const __half2* hp = (const __half2*)&u1;
                    #pragma unroll
                    for (int r = 0; r < 4; ++r) {
                        float2 fv = __half22float2(hp[r]);
                        f[2 * r] += fv.x; f[2 * r + 1] += fv.y;
                    }
                }
            }
        } else {
            if (q == 0) {
                float di0 = dinv[node];
                float4 a = x4[node * 16 + 2 * col];
                float4 b = x4[node * 16 + 2 * col + 1];
                f[0] = di0 * a.x; f[1] = di0 * a.y; f[2] = di0 * a.z; f[3] = di0 * a.w;
                f[4] = di0 * b.x; f[5] = di0 * b.y; f[6] = di0 * b.z; f[7] = di0 * b.w;
            }
            int p = beg + q;
            int s0 = (p < end) ? csr[p] : -1;
            int s1 = (p + 8 < end) ? csr[p + 8] : -1;
            for (int cb = beg; cb < end; cb += 16) {
                int c0 = s0, c1 = s1;
                int np = cb + 16 + q;
                s0 = (np < end) ? csr[np] : -1;
                s1 = (np + 8 < end) ? csr[np + 8] : -1;
                if (c0 >= 0) {
                    float w = dinv[c0];
                    float4 a = x4[c0 * 16 + 2 * col];
                    float4 b = x4[c0 * 16 + 2 * col + 1];
                    f[0] += w * a.x; f[1] += w * a.y; f[2] += w * a.z; f[3] += w * a.w;
                    f[4] += w * b.x; f[5] += w * b.y; f[6] += w * b.z; f[7] += w * b.w;
                }
                if (c1 >= 0) {
                    float w = dinv[c1];
                    float4 a = x4[c1 * 16 + 2 * col];
                    float4 b = x4[c1 * 16 + 2 * col + 1];
                    f[0] += w * a.x; f[1] += w * a.y; f[2] += w * a.z; f[3] += w * a.w;
                    f[4] += w * b.x; f[5] += w * b.y; f[6] += w * b.z; f[7] += w * b.w;
                }
            }
        }
        #pragma unroll
        for (int off = 8; off < 64; off <<= 1) {
            #pragma unroll
            for (int r = 0; r < 8; ++r) f[r] += __shfl_xor(f[r], off, 64);
        }
        if (lane < 8) {
            float di = dinv[node];
            union { uint4 u; __half2 h[4]; } pk;
            #pragma unroll
            for (int r = 0; r < 4; ++r)
                pk.h[r] = __floats2half2_rn(di * f[2 * r], di * f[2 * r + 1]);
            Atile[m * 9 + lane] = pk.u;
        }
    }
    __syncthreads();
    if (t >= 64) return;

    int mm = lane & 15, kq = lane >> 4;
    half8 A0 = as_half8(Atile[mm * 9 + kq]);
    half8 A1 = as_half8(Atile[mm * 9 + 4 + kq]);
    f32x4 acc[8];
    #pragma unroll
    for (int cb = 0; cb < 8; ++cb) acc[cb] = (f32x4){0.f, 0.f, 0.f, 0.f};
    #pragma unroll
    for (int cb = 0; cb < 8; ++cb) {
        half8 bh0 = as_half8(Wpk[(cb * 2 + 0) * 64 + lane]);
        half8 bh1 = as_half8(Wpk[(cb * 2 + 1) * 64 + lane]);
        half8 bl0 = as_half8(Wpk[1024 + (cb * 2 + 0) * 64 + lane]);
        half8 bl1 = as_half8(Wpk[1024 + (cb * 2 + 1) * 64 + lane]);
        acc[cb] = __builtin_amdgcn_mfma_f32_16x16x32_f16(A0, bh0, acc[cb], 0, 0, 0);
        acc[cb] = __builtin_amdgcn_mfma_f32_16x16x32_f16(A1, bh1, acc[cb], 0, 0, 0);
        acc[cb] = __builtin_amdgcn_mfma_f32_16x16x32_f16(A0, bl0, acc[cb], 0, 0, 0);
        acc[cb] = __builtin_amdgcn_mfma_f32_16x16x32_f16(A1, bl1, acc[cb], 0, 0, 0);
    }
    float zp[4] = {0.f, 0.f, 0.f, 0.f};
    #pragma unroll
    for (int cb = 0; cb < 8; ++cb) {
        int colg = cb * 16 + mm;
        float bb = b1[colg], vv = v[colg];
        #pragma unroll
        for (int r = 0; r < 4; ++r) {
            float h = acc[cb][r] + bb;
            h = fmaxf(h, 0.f);
            zp[r] += h * vv;
        }
    }
    #pragma unroll
    for (int off = 1; off < 16; off <<= 1) {
        #pragma unroll
        for (int r = 0; r < 4; ++r) zp[r] += __shfl_xor(zp[r], off, 64);
    }
    if (mm == 0) {
        int nb = node0 + kq * 4;
        #pragma unroll
        for (int r = 0; r < 4; ++r) zz[nb + r] = dinv[nb + r] * zp[r];
    }
}

// Layer 2 (collapsed): out[i] = c + dinv[i]*(zz[i] + sum_in zz[s]). 16 lanes/node.
__global__ void out_kernel(const int* __restrict__ row_ptr, const int* __restrict__ csr,
                           const float* __restrict__ dinv, const float* __restrict__ zz,
                           const float* __restrict__ c, float* __restrict__ out, int n) {
    int tid = blockIdx.x * blockDim.x + threadIdx.x;
    int node = tid >> 4;
    int sub = tid & 15;
    if (node >= n) return;
    int beg = row_ptr[node], end = row_ptr[node + 1];
    float acc = 0.f;
    for (int e = beg + sub; e < end; e += 16) acc += zz[csr[e]];
    acc += __shfl_xor(acc, 1, 64);
    acc += __shfl_xor(acc, 2, 64);
    acc += __shfl_xor(acc, 4, 64);
    acc += __shfl_xor(acc, 8, 64);
    if (sub == 0) out[node] = c[0] + dinv[node] * (acc + zz[node]);
}

extern "C" void kernel_launch(void* const* d_in, const int* in_sizes, int n_in,
                              void* d_out, int out_size, void* d_ws, size_t ws_size,
                              hipStream_t stream) {
    const float* x  = (const float*)d_in[0];
    const int*   ei = (const int*)d_in[1];
    const float* W1 = (const float*)d_in[2];
    const float* b1 = (const float*)d_in[3];
    const float* W2 = (const float*)d_in[4];
    const float* b2 = (const float*)d_in[5];
    const float* Wl = (const float*)d_in[6];
    const float* bl = (const float*)d_in[7];
    float* out = (float*)d_out;

    int E = in_sizes[1] / 2;
    const int* src = ei;
    const int* dst = ei + E;

    float* ws      = (float*)d_ws;
    float* dinv    = ws;                       // N
    int*   row_ptr = (int*)(ws + N_NODES);     // N+4
    int*   cnt     = row_ptr + N_NODES + 4;    // N
    int*   bsum    = cnt + N_NODES;            // 128
    float* zz      = (float*)(bsum + 128);     // N
    float* v       = zz + N_NODES;             // 128
    float* c       = v + HID;                  // 4
    int*   bcur    = (int*)(c + 4);            // 512 (NBUCKETS=391 padded)
    int*   csr     = bcur + 512;               // E
    float* after   = (float*)(csr + E);
    uint4* Wpk     = (uint4*)after;            // 2048 uint4 (32 KB)
    __half* y      = (__half*)(after + 8192);  // N*64 halves

    size_t base_floats = (size_t)N_NODES * 3 + 4 + 128 + 128 + 4 + 512 + (size_t)E + 8192;
    size_t need_f16 = (base_floats + (size_t)N_NODES * 32) * 4;
    bool use_f16 = (ws_size >= need_f16);
    int n16 = use_f16 ? N_NODES * 16 : 0;

    int nscan = (N_NODES + SCAN_CHUNK - 1) / SCAN_CHUNK;  // 98
    int prep_blocks = 9 + (n16 + 255) / 256;
    int nchunks = (E + ACHUNK - 1) / ACHUNK;              // 391

    hipMemsetAsync(cnt, 0, sizeof(int) * N_NODES, stream);
    hist_kernel<<<(E + 255) / 256, 256, 0, stream>>>(dst, cnt, E);
    scan1_kernel<<<nscan, 256, 0, stream>>>(cnt, row_ptr, bsum, dinv, N_NODES);
    prep_kernel<<<prep_blocks, 256, 0, stream>>>(
        bsum, nscan, W1, W2, b2, Wl, bl, v, c, Wpk,
        (const float4*)x, (__half2*)y, dinv, n16);
    scan3_kernel<<<(N_NODES + 255) / 256, 256, 0, stream>>>(row_ptr, bsum, bcur, N_NODES, E);
    partA_kernel<<<nchunks, 256, 0, stream>>>(src, dst, bcur, (unsigned int*)csr, E);
    partB_kernel<<<NBUCKETS, 256, 0, stream>>>(row_ptr, (unsigned int*)csr, N_NODES);
    fused1_kernel<<<N_NODES / 16, 256, 0, stream>>>(
        use_f16 ? (const uint4*)y : nullptr, (const float4*)x,
        row_ptr, csr, dinv, Wpk, b1, v, zz, N_NODES);
    out_kernel<<<(N_NODES * 16 + 255) / 256, 256, 0, stream>>>(
        row_ptr, csr, dinv, zz, c, out, N_NODES);
}

// Round 10
// 271.691 us; speedup vs baseline: 2.9761x; 1.0078x over previous
//
#include <hip/hip_runtime.h>
#include <hip/hip_fp16.h>

// GCN 2-layer, N=100000, F=64, H=128, O=100, out [N,1] fp32.
// out = agg(relu(agg(x)@W1 + b1) . (W2@Wl)) + (b2@Wl + bl)
// agg via CSR-by-dst GATHER; layer-1 GEMV via MFMA (fp16 hi+lo split W1).
// CSR built bucket-wise with NO per-node global pass:
//   bhist (LDS hist -> count matrix, zero atomics) -> bscan (bucket bases)
//   -> partA (LDS multi-split, 1 reserve-atomic/bucket/block)
//   -> partB (in-bucket counting sort; also emits row_ptr, dinv, fp16 y).

#define N_NODES 100000
#define F_IN 64
#define HID 128
#define OUT2 100
#define BSHIFT 8
#define BNODES 256
#define NBUCKETS ((N_NODES + BNODES - 1) / BNODES)  // 391
#define BCAP 9216   // partB LDS staging cap (bucket mean 4096, sigma ~64)
#define ACHUNK 4096 // edges per block in bhist/partA
#define NB_PAD 512
#define BMROW 392   // bmat row stride (ints)
#define SENTB 0xFFFFu

typedef _Float16 half8 __attribute__((ext_vector_type(8)));
typedef float f32x4 __attribute__((ext_vector_type(4)));

static __device__ __forceinline__ half8 as_half8(uint4 u) {
    union { uint4 u; half8 h; } x; x.u = u; return x.h;
}

// Per-chunk bucket histogram: zero global atomics. bmat[chunk][bin].
__global__ __launch_bounds__(256) void bhist_kernel(
    const int* __restrict__ dst, int* __restrict__ bmat, int E) {
    __shared__ int hist[BMROW];
    int t = threadIdx.x;
    hist[t] = 0;
    if (t + 256 < BMROW) hist[t + 256] = 0;
    __syncthreads();
    int base = blockIdx.x * ACHUNK;
    #pragma unroll
    for (int k = 0; k < 16; ++k) {
        int e = base + k * 256 + t;
        if (e < E) atomicAdd(&hist[dst[e] >> BSHIFT], 1);
    }
    __syncthreads();
    int* row = bmat + blockIdx.x * BMROW;
    row[t] = hist[t];
    if (t + 256 < BMROW) row[t + 256] = hist[t + 256];
}

// Single block: column-reduce bmat (coalesced across threads) + scan -> bases.
__global__ __launch_bounds__(512) void bscan_kernel(
    const int* __restrict__ bmat, int* __restrict__ bbase, int* __restrict__ bcur,
    int nchunks, int E) {
    __shared__ int ls[512];
    int t = threadIdx.x;
    int acc = 0;
    if (t < NBUCKETS)
        for (int r = 0; r < nchunks; ++r) acc += bmat[r * BMROW + t];
    ls[t] = acc;
    __syncthreads();
    for (int off = 1; off < 512; off <<= 1) {
        int v = (t >= off) ? ls[t - off] : 0;
        __syncthreads();
        ls[t] += v;
        __syncthreads();
    }
    int excl = ls[t] - acc;
    if (t < NBUCKETS) { bbase[t] = excl; bcur[t] = excl; }
    if (t == NBUCKETS - 1) bbase[NBUCKETS] = excl + acc;  // = E
}

// Blocks 0..7: pack W1 into MFMA B-fragment layout, fp16 hi+lo split.
// Block 8: v = W2@Wl (t<128), c = b2.Wl + bl (t==128).
__global__ __launch_bounds__(256) void prep_kernel(
    const float* __restrict__ W1, const float* __restrict__ W2,
    const float* __restrict__ b2, const float* __restrict__ Wl,
    const float* __restrict__ bl,
    float* __restrict__ v, float* __restrict__ c, uint4* __restrict__ Wpk) {
    int t = threadIdx.x;
    if (blockIdx.x < 8) {
        // idx: bit10 = part (0=hi,1=lo), bits9..7 = cb, bit6 = kf, bits5..0 = lane
        int idx = blockIdx.x * 256 + t;
        int lane2 = idx & 63;
        int kf    = (idx >> 6) & 1;
        int cb    = (idx >> 7) & 7;
        int part  = (idx >> 10) & 1;
        union { uint4 u; unsigned short s[8]; } pk;
        #pragma unroll
        for (int j = 0; j < 8; ++j) {
            int k    = kf * 32 + (lane2 >> 4) * 8 + j;
            int colg = cb * 16 + (lane2 & 15);
            float w = W1[k * HID + colg];
            __half h = __float2half_rn(w);
            if (part) h = __float2half_rn(w - __half2float(h));
            pk.s[j] = __half_as_ushort(h);
        }
        Wpk[idx] = pk.u;
    } else {
        if (t < HID) {
            float acc = 0.f;
            for (int k = 0; k < OUT2; ++k) acc += W2[t * OUT2 + k] * Wl[k];
            v[t] = acc;
        } else if (t == HID) {
            float acc = bl[0];
            for (int k = 0; k < OUT2; ++k) acc += b2[k] * Wl[k];
            *c = acc;
        }
    }
}

// Pass A: LDS multi-split into dst-buckets; ONE reserve-atomic per bucket
// per block. Packed entry = (src<<8) | (dst&255).
__global__ __launch_bounds__(256) void partA_kernel(
    const int* __restrict__ src, const int* __restrict__ dst,
    int* __restrict__ bcur, unsigned int* __restrict__ ebuf, int E) {
    __shared__ unsigned int stage[ACHUNK];       // 16 KB
    __shared__ unsigned short sb[ACHUNK];        // 8 KB
    __shared__ int hist[NB_PAD];
    __shared__ int ocnt[NB_PAD];
    __shared__ int gbase[NB_PAD];
    __shared__ int cnt2[NB_PAD];
    int t = threadIdx.x;
    int base = blockIdx.x * ACHUNK;
    int total = E - base; if (total > ACHUNK) total = ACHUNK;

    hist[t] = 0; hist[t + 256] = 0;
    cnt2[t] = 0; cnt2[t + 256] = 0;
    __syncthreads();

    unsigned int pe[16];
    unsigned short bk[16];
    #pragma unroll
    for (int k = 0; k < 16; ++k) {
        int e = base + k * 256 + t;
        if (e < E) {
            int s = src[e], d = dst[e];
            pe[k] = ((unsigned int)s << 8) | (unsigned int)(d & (BNODES - 1));
            bk[k] = (unsigned short)(d >> BSHIFT);
            atomicAdd(&hist[bk[k]], 1);
        } else {
            bk[k] = SENTB;
        }
    }
    __syncthreads();
    ocnt[t] = hist[t]; ocnt[t + 256] = hist[t + 256];
    __syncthreads();
    for (int off = 1; off < NB_PAD; off <<= 1) {
        int v0 = (t >= off) ? hist[t - off] : 0;
        int v1 = hist[t + 256 - off];
        __syncthreads();
        hist[t] += v0; hist[t + 256] += v1;
        __syncthreads();
    }
    #pragma unroll
    for (int i = 0; i < 2; ++i) {
        int b = (t + i * 256 + blockIdx.x * 131) & (NB_PAD - 1);
        int cc = ocnt[b];
        if (cc > 0 && b < NBUCKETS) gbase[b] = atomicAdd(&bcur[b], cc);
    }
    __syncthreads();
    #pragma unroll
    for (int k = 0; k < 16; ++k) {
        if (bk[k] != SENTB) {
            int b = bk[k];
            int pos = (hist[b] - ocnt[b]) + atomicAdd(&cnt2[b], 1);
            stage[pos] = pe[k];
            sb[pos] = (unsigned short)b;
        }
    }
    __syncthreads();
    #pragma unroll
    for (int k = 0; k < 16; ++k) {
        int idx = k * 256 + t;
        if (idx < total) {
            int b = sb[idx];
            int lo = hist[b] - ocnt[b];
            ebuf[gbase[b] + (idx - lo)] = stage[idx];
        }
    }
}

// Pass B: one block per bucket, in-place counting sort; ALSO emits
// row_ptr + dinv for its 256 nodes and the fp16 pre-scaled y rows.
__global__ __launch_bounds__(256) void partB_kernel(
    const int* __restrict__ bbase, unsigned int* __restrict__ csr,
    int* __restrict__ row_ptr, float* __restrict__ dinv,
    const float4* __restrict__ x4, __half2* __restrict__ y2,
    int n, int E, int do_y) {
    __shared__ int lcnt[BNODES];
    __shared__ int lscan[BNODES];
    __shared__ int lcur[BNODES];
    __shared__ float sdinv[BNODES];
    __shared__ unsigned int sbuf[BCAP];
    int b = blockIdx.x, t = threadIdx.x;
    int node0 = b << BSHIFT;
    int nlocal = min(BNODES, n - node0);
    int base = bbase[b];
    int endp = bbase[b + 1];
    int cnt = endp - base;
    lcnt[t] = 0;
    __syncthreads();
    unsigned int er[BCAP / 256];
    #pragma unroll
    for (int k = 0; k < BCAP / 256; ++k) {
        int idx = k * 256 + t;
        er[k] = (idx < cnt) ? csr[base + idx] : 0xFFFFFFFFu;
        if (er[k] != 0xFFFFFFFFu) atomicAdd(&lcnt[er[k] & (BNODES - 1)], 1);
    }
    __syncthreads();
    int own = lcnt[t];
    sdinv[t] = rsqrtf((float)own + 1.0f);
    lscan[t] = own;
    __syncthreads();
    for (int off = 1; off < BNODES; off <<= 1) {
        int v = (t >= off) ? lscan[t - off] : 0;
        __syncthreads();
        lscan[t] += v;
        __syncthreads();
    }
    int excl = lscan[t] - own;
    lcur[t] = excl;
    if (t < nlocal) {
        row_ptr[node0 + t] = base + excl;
        dinv[node0 + t] = sdinv[t];
    }
    if (t == 0 && node0 + nlocal == n) row_ptr[n] = E;
    __syncthreads();
    #pragma unroll
    for (int k = 0; k < BCAP / 256; ++k) {
        unsigned int e = er[k];
        if (e != 0xFFFFFFFFu) {
            int p = atomicAdd(&lcur[(int)(e & (BNODES - 1))], 1);
            sbuf[p] = e >> 8;
        }
    }
    __syncthreads();
    for (int idx = t; idx < cnt; idx += 256) csr[base + idx] = sbuf[idx];
    if (do_y) {
        for (int i = t; i < nlocal * 16; i += 256) {
            int nl = i >> 4;
            int gi = (node0 + nl) * 16 + (i & 15);
            float di = sdinv[nl];
            float4 xv = x4[gi];
            y2[2 * gi]     = __floats2half2_rn(xv.x * di, xv.y * di);
            y2[2 * gi + 1] = __floats2half2_rn(xv.z * di, xv.w * di);
        }
    }
}

// Fused layer 1: block = 4 waves = 16 nodes (one MFMA tile).
__global__ __launch_bounds__(256) void fused1_kernel(
    const uint4* __restrict__ y, const float4* __restrict__ x4,
    const int* __restrict__ row_ptr, const int* __restrict__ csr,
    const float* __restrict__ dinv, const uint4* __restrict__ Wpk,
    const float* __restrict__ b1, const float* __restrict__ v,
    float* __restrict__ zz, int n) {
    __shared__ uint4 Atile[16 * 9];
    int t = threadIdx.x;
    int lane = t & 63;
    int wave = t >> 6;
    int node0 = blockIdx.x * 16;
    int q = lane >> 3, col = lane & 7;

    #pragma unroll
    for (int j = 0; j < 4; ++j) {
        int m = wave * 4 + j;
        int node = node0 + m;
        float f[8];
        #pragma unroll
        for (int r = 0; r < 8; ++r) f[r] = 0.f;
        int beg = row_ptr[node], end = row_ptr[node + 1];
        if (y) {
            if (q == 0) {
                uint4 u = y[node * 8 + col];
                const __half2* hp = (const __half2*)&u;
                #pragma unroll
                for (int r = 0; r < 4; ++r) {
                    float2 fv = __half22float2(hp[r]);
                    f[2 * r] = fv.x; f[2 * r + 1] = fv.y;
                }
            }
            int p = beg + q;
            int s0 = (p < end) ? csr[p] : -1;
            int s1 = (p + 8 < end) ? csr[p + 8] : -1;
            for (int cb = beg; cb < end; cb += 16) {
                int c0 = s0, c1 = s1;
                int np = cb + 16 + q;
                s0 = (np < end) ? csr[np] : -1;
                s1 = (np + 8 < end) ? csr[np + 8] : -1;
                uint4 u0, u1;
                if (c0 >= 0) u0 = y[c0 * 8 + col];
                if (c1 >= 0) u1 = y[c1 * 8 + col];
                if (c0 >= 0) {
                    const __half2* hp = (const __half2*)&u0;
                    #pragma unroll
                    for (int r = 0; r < 4; ++r) {
                        float2 fv = __half22float2(hp[r]);
                        f[2 * r] += fv.x; f[2 * r + 1] += fv.y;
                    }
                }
                if (c1 >= 0) {
                    const __half2* hp = (const __half2*)&u1;
                    #pragma unroll
                    for (int r = 0; r < 4; ++r) {
                        float2 fv = __half22float2(hp[r]);
                        f[2 * r] += fv.x; f[2 * r + 1] += fv.y;
                    }
                }
            }
        } else {
            if (q == 0) {
                float di0 = dinv[node];
                float4 a = x4[node * 16 + 2 * col];
                float4 b = x4[node * 16 + 2 * col + 1];
                f[0] = di0 * a.x; f[1] = di0 * a.y; f[2] = di0 * a.z; f[3] = di0 * a.w;
                f[4] = di0 * b.x; f[5] = di0 * b.y; f[6] = di0 * b.z; f[7] = di0 * b.w;
            }
            int p = beg + q;
            int s0 = (p < end) ? csr[p] : -1;
            int s1 = (p + 8 < end) ? csr[p + 8] : -1;
            for (int cb = beg; cb < end; cb += 16) {
                int c0 = s0, c1 = s1;
                int np = cb + 16 + q;
                s0 = (np < end) ? csr[np] : -1;
                s1 = (np + 8 < end) ? csr[np + 8] : -1;
                if (c0 >= 0) {
                    float w = dinv[c0];
                    float4 a = x4[c0 * 16 + 2 * col];
                    float4 b = x4[c0 * 16 + 2 * col + 1];
                    f[0] += w * a.x; f[1] += w * a.y; f[2] += w * a.z; f[3] += w * a.w;
                    f[4] += w * b.x; f[5] += w * b.y; f[6] += w * b.z; f[7] += w * b.w;
                }
                if (c1 >= 0) {
                    float w = dinv[c1];
                    float4 a = x4[c1 * 16 + 2 * col];
                    float4 b = x4[c1 * 16 + 2 * col + 1];
                    f[0] += w * a.x; f[1] += w * a.y; f[2] += w * a.z; f[3] += w * a.w;
                    f[4] += w * b.x; f[5] += w * b.y; f[6] += w * b.z; f[7] += w * b.w;
                }
            }
        }
        #pragma unroll
        for (int off = 8; off < 64; off <<= 1) {
            #pragma unroll
            for (int r = 0; r < 8; ++r) f[r] += __shfl_xor(f[r], off, 64);
        }
        if (lane < 8) {
            float di = dinv[node];
            union { uint4 u; __half2 h[4]; } pk;
            #pragma unroll
            for (int r = 0; r < 4; ++r)
                pk.h[r] = __floats2half2_rn(di * f[2 * r], di * f[2 * r + 1]);
            Atile[m * 9 + lane] = pk.u;
        }
    }
    __syncthreads();
    if (t >= 64) return;

    int mm = lane & 15, kq = lane >> 4;
    half8 A0 = as_half8(Atile[mm * 9 + kq]);
    half8 A1 = as_half8(Atile[mm * 9 + 4 + kq]);
    f32x4 acc[8];
    #pragma unroll
    for (int cb = 0; cb < 8; ++cb) acc[cb] = (f32x4){0.f, 0.f, 0.f, 0.f};
    #pragma unroll
    for (int cb = 0; cb < 8; ++cb) {
        half8 bh0 = as_half8(Wpk[(cb * 2 + 0) * 64 + lane]);
        half8 bh1 = as_half8(Wpk[(cb * 2 + 1) * 64 + lane]);
        half8 bl0 = as_half8(Wpk[1024 + (cb * 2 + 0) * 64 + lane]);
        half8 bl1 = as_half8(Wpk[1024 + (cb * 2 + 1) * 64 + lane]);
        acc[cb] = __builtin_amdgcn_mfma_f32_16x16x32_f16(A0, bh0, acc[cb], 0, 0, 0);
        acc[cb] = __builtin_amdgcn_mfma_f32_16x16x32_f16(A1, bh1, acc[cb], 0, 0, 0);
        acc[cb] = __builtin_amdgcn_mfma_f32_16x16x32_f16(A0, bl0, acc[cb], 0, 0, 0);
        acc[cb] = __builtin_amdgcn_mfma_f32_16x16x32_f16(A1, bl1, acc[cb], 0, 0, 0);
    }
    float zp[4] = {0.f, 0.f, 0.f, 0.f};
    #pragma unroll
    for (int cb = 0; cb < 8; ++cb) {
        int colg = cb * 16 + mm;
        float bb = b1[colg], vv = v[colg];
        #pragma unroll
        for (int r = 0; r < 4; ++r) {
            float h = acc[cb][r] + bb;
            h = fmaxf(h, 0.f);
            zp[r] += h * vv;
        }
    }
    #pragma unroll
    for (int off = 1; off < 16; off <<= 1) {
        #pragma unroll
        for (int r = 0; r < 4; ++r) zp[r] += __shfl_xor(zp[r], off, 64);
    }
    if (mm == 0) {
        int nb = node0 + kq * 4;
        #pragma unroll
        for (int r = 0; r < 4; ++r) zz[nb + r] = dinv[nb + r] * zp[r];
    }
}

// Layer 2 (collapsed): out[i] = c + dinv[i]*(zz[i] + sum_in zz[s]). 16 lanes/node.
__global__ void out_kernel(const int* __restrict__ row_ptr, const int* __restrict__ csr,
                           const float* __restrict__ dinv, const float* __restrict__ zz,
                           const float* __restrict__ c, float* __restrict__ out, int n) {
    int tid = blockIdx.x * blockDim.x + threadIdx.x;
    int node = tid >> 4;
    int sub = tid & 15;
    if (node >= n) return;
    int beg = row_ptr[node], end = row_ptr[node + 1];
    float acc = 0.f;
    for (int e = beg + sub; e < end; e += 16) acc += zz[csr[e]];
    acc += __shfl_xor(acc, 1, 64);
    acc += __shfl_xor(acc, 2, 64);
    acc += __shfl_xor(acc, 4, 64);
    acc += __shfl_xor(acc, 8, 64);
    if (sub == 0) out[node] = c[0] + dinv[node] * (acc + zz[node]);
}

extern "C" void kernel_launch(void* const* d_in, const int* in_sizes, int n_in,
                              void* d_out, int out_size, void* d_ws, size_t ws_size,
                              hipStream_t stream) {
    const float* x  = (const float*)d_in[0];
    const int*   ei = (const int*)d_in[1];
    const float* W1 = (const float*)d_in[2];
    const float* b1 = (const float*)d_in[3];
    const float* W2 = (const float*)d_in[4];
    const float* b2 = (const float*)d_in[5];
    const float* Wl = (const float*)d_in[6];
    const float* bl = (const float*)d_in[7];
    float* out = (float*)d_out;

    int E = in_sizes[1] / 2;
    const int* src = ei;
    const int* dst = ei + E;
    int Epad = (E + 3) & ~3;

    float* ws      = (float*)d_ws;
    float* dinv    = ws;                       // N
    int*   row_ptr = (int*)(ws + N_NODES);     // N+4
    float* zz      = (float*)(row_ptr + N_NODES + 4);  // N
    float* v       = zz + N_NODES;             // 128
    float* c       = v + HID;                  // 4
    int*   bbase   = (int*)(c + 4);            // 512
    int*   bcur    = bbase + 512;              // 512
    int*   csr     = bcur + 512;               // Epad (bmat overlays: 391*392 ints << E)
    int*   bmat    = csr;                      // overlay: used only before partA
    uint4* Wpk     = (uint4*)(csr + Epad);     // 2048 uint4 (32 KB)
    __half* y      = (__half*)((float*)Wpk + 8192);  // N*64 halves

    size_t base_floats = (size_t)N_NODES * 3 + 4 + 128 + 4 + 1024 + (size_t)Epad + 8192;
    size_t need_f16 = (base_floats + (size_t)N_NODES * 32) * 4;
    bool use_f16 = (ws_size >= need_f16);

    int nchunks = (E + ACHUNK - 1) / ACHUNK;   // 391

    prep_kernel<<<9, 256, 0, stream>>>(W1, W2, b2, Wl, bl, v, c, Wpk);
    bhist_kernel<<<nchunks, 256, 0, stream>>>(dst, bmat, E);
    bscan_kernel<<<1, 512, 0, stream>>>(bmat, bbase, bcur, nchunks, E);
    partA_kernel<<<nchunks, 256, 0, stream>>>(src, dst, bcur, (unsigned int*)csr, E);
    partB_kernel<<<NBUCKETS, 256, 0, stream>>>(
        bbase, (unsigned int*)csr, row_ptr, dinv,
        (const float4*)x, (__half2*)y, N_NODES, E, use_f16 ? 1 : 0);
    fused1_kernel<<<N_NODES / 16, 256, 0, stream>>>(
        use_f16 ? (const uint4*)y : nullptr, (const float4*)x,
        row_ptr, csr, dinv, Wpk, b1, v, zz, N_NODES);
    out_kernel<<<(N_NODES * 16 + 255) / 256, 256, 0, stream>>>(
        row_ptr, csr, dinv, zz, c, out, N_NODES);
}

// Round 11
// 257.356 us; speedup vs baseline: 3.1419x; 1.0557x over previous
//
#include <hip/hip_runtime.h>
#include <hip/hip_fp16.h>

// GCN 2-layer, N=100000, F=64, H=128, O=100, out [N,1] fp32.
// out = agg(relu(agg(x)@W1 + b1) . (W2@Wl)) + (b2@Wl + bl)
// agg via CSR-by-dst GATHER; layer-1 GEMV via MFMA (fp16 hi+lo split W1).
// CSR built bucket-wise (bhist -> bscan -> partA multi-split -> partB sort).
// fused1 gather phase interleaves its 4 nodes for 4x memory-level parallelism.

#define N_NODES 100000
#define F_IN 64
#define HID 128
#define OUT2 100
#define BSHIFT 8
#define BNODES 256
#define NBUCKETS ((N_NODES + BNODES - 1) / BNODES)  // 391
#define BCAP 9216   // partB LDS staging cap (bucket mean 4096, sigma ~64)
#define ACHUNK 4096 // edges per block in bhist/partA
#define NB_PAD 512
#define BMROW 392   // bmat row stride (ints)
#define SENTB 0xFFFFu

typedef _Float16 half8 __attribute__((ext_vector_type(8)));
typedef float f32x4 __attribute__((ext_vector_type(4)));

static __device__ __forceinline__ half8 as_half8(uint4 u) {
    union { uint4 u; half8 h; } x; x.u = u; return x.h;
}

static __device__ __forceinline__ void accum8(float* f, uint4 u) {
    const __half2* hp = (const __half2*)&u;
    #pragma unroll
    for (int r = 0; r < 4; ++r) {
        float2 fv = __half22float2(hp[r]);
        f[2 * r] += fv.x; f[2 * r + 1] += fv.y;
    }
}

// Per-chunk bucket histogram: zero global atomics. bmat[chunk][bin].
__global__ __launch_bounds__(256) void bhist_kernel(
    const int* __restrict__ dst, int* __restrict__ bmat, int E) {
    __shared__ int hist[BMROW];
    int t = threadIdx.x;
    hist[t] = 0;
    if (t + 256 < BMROW) hist[t + 256] = 0;
    __syncthreads();
    int base = blockIdx.x * ACHUNK;
    #pragma unroll
    for (int k = 0; k < 16; ++k) {
        int e = base + k * 256 + t;
        if (e < E) atomicAdd(&hist[dst[e] >> BSHIFT], 1);
    }
    __syncthreads();
    int* row = bmat + blockIdx.x * BMROW;
    row[t] = hist[t];
    if (t + 256 < BMROW) row[t + 256] = hist[t + 256];
}

// Single block: column-reduce bmat (coalesced across threads) + scan -> bases.
__global__ __launch_bounds__(512) void bscan_kernel(
    const int* __restrict__ bmat, int* __restrict__ bbase, int* __restrict__ bcur,
    int nchunks, int E) {
    __shared__ int ls[512];
    int t = threadIdx.x;
    int acc = 0;
    if (t < NBUCKETS)
        for (int r = 0; r < nchunks; ++r) acc += bmat[r * BMROW + t];
    ls[t] = acc;
    __syncthreads();
    for (int off = 1; off < 512; off <<= 1) {
        int v = (t >= off) ? ls[t - off] : 0;
        __syncthreads();
        ls[t] += v;
        __syncthreads();
    }
    int excl = ls[t] - acc;
    if (t < NBUCKETS) { bbase[t] = excl; bcur[t] = excl; }
    if (t == NBUCKETS - 1) bbase[NBUCKETS] = excl + acc;  // = E
}

// Blocks 0..7: pack W1 into MFMA B-fragment layout, fp16 hi+lo split.
// Block 8: v = W2@Wl (t<128), c = b2.Wl + bl (t==128).
__global__ __launch_bounds__(256) void prep_kernel(
    const float* __restrict__ W1, const float* __restrict__ W2,
    const float* __restrict__ b2, const float* __restrict__ Wl,
    const float* __restrict__ bl,
    float* __restrict__ v, float* __restrict__ c, uint4* __restrict__ Wpk) {
    int t = threadIdx.x;
    if (blockIdx.x < 8) {
        // idx: bit10 = part (0=hi,1=lo), bits9..7 = cb, bit6 = kf, bits5..0 = lane
        int idx = blockIdx.x * 256 + t;
        int lane2 = idx & 63;
        int kf    = (idx >> 6) & 1;
        int cb    = (idx >> 7) & 7;
        int part  = (idx >> 10) & 1;
        union { uint4 u; unsigned short s[8]; } pk;
        #pragma unroll
        for (int j = 0; j < 8; ++j) {
            int k    = kf * 32 + (lane2 >> 4) * 8 + j;
            int colg = cb * 16 + (lane2 & 15);
            float w = W1[k * HID + colg];
            __half h = __float2half_rn(w);
            if (part) h = __float2half_rn(w - __half2float(h));
            pk.s[j] = __half_as_ushort(h);
        }
        Wpk[idx] = pk.u;
    } else {
        if (t < HID) {
            float acc = 0.f;
            for (int k = 0; k < OUT2; ++k) acc += W2[t * OUT2 + k] * Wl[k];
            v[t] = acc;
        } else if (t == HID) {
            float acc = bl[0];
            for (int k = 0; k < OUT2; ++k) acc += b2[k] * Wl[k];
            *c = acc;
        }
    }
}

// Pass A: LDS multi-split into dst-buckets; ONE reserve-atomic per bucket
// per block. Packed entry = (src<<8) | (dst&255).
__global__ __launch_bounds__(256) void partA_kernel(
    const int* __restrict__ src, const int* __restrict__ dst,
    int* __restrict__ bcur, unsigned int* __restrict__ ebuf, int E) {
    __shared__ unsigned int stage[ACHUNK];       // 16 KB
    __shared__ unsigned short sb[ACHUNK];        // 8 KB
    __shared__ int hist[NB_PAD];
    __shared__ int ocnt[NB_PAD];
    __shared__ int gbase[NB_PAD];
    __shared__ int cnt2[NB_PAD];
    int t = threadIdx.x;
    int base = blockIdx.x * ACHUNK;
    int total = E - base; if (total > ACHUNK) total = ACHUNK;

    hist[t] = 0; hist[t + 256] = 0;
    cnt2[t] = 0; cnt2[t + 256] = 0;
    __syncthreads();

    unsigned int pe[16];
    unsigned short bk[16];
    #pragma unroll
    for (int k = 0; k < 16; ++k) {
        int e = base + k * 256 + t;
        if (e < E) {
            int s = src[e], d = dst[e];
            pe[k] = ((unsigned int)s << 8) | (unsigned int)(d & (BNODES - 1));
            bk[k] = (unsigned short)(d >> BSHIFT);
            atomicAdd(&hist[bk[k]], 1);
        } else {
            bk[k] = SENTB;
        }
    }
    __syncthreads();
    ocnt[t] = hist[t]; ocnt[t + 256] = hist[t + 256];
    __syncthreads();
    for (int off = 1; off < NB_PAD; off <<= 1) {
        int v0 = (t >= off) ? hist[t - off] : 0;
        int v1 = hist[t + 256 - off];
        __syncthreads();
        hist[t] += v0; hist[t + 256] += v1;
        __syncthreads();
    }
    #pragma unroll
    for (int i = 0; i < 2; ++i) {
        int b = (t + i * 256 + blockIdx.x * 131) & (NB_PAD - 1);
        int cc = ocnt[b];
        if (cc > 0 && b < NBUCKETS) gbase[b] = atomicAdd(&bcur[b], cc);
    }
    __syncthreads();
    #pragma unroll
    for (int k = 0; k < 16; ++k) {
        if (bk[k] != SENTB) {
            int b = bk[k];
            int pos = (hist[b] - ocnt[b]) + atomicAdd(&cnt2[b], 1);
            stage[pos] = pe[k];
            sb[pos] = (unsigned short)b;
        }
    }
    __syncthreads();
    #pragma unroll
    for (int k = 0; k < 16; ++k) {
        int idx = k * 256 + t;
        if (idx < total) {
            int b = sb[idx];
            int lo = hist[b] - ocnt[b];
            ebuf[gbase[b] + (idx - lo)] = stage[idx];
        }
    }
}

// Pass B: one block per bucket, in-place counting sort; ALSO emits
// row_ptr + dinv for its 256 nodes and the fp16 pre-scaled y rows.
__global__ __launch_bounds__(256) void partB_kernel(
    const int* __restrict__ bbase, unsigned int* __restrict__ csr,
    int* __restrict__ row_ptr, float* __restrict__ dinv,
    const float4* __restrict__ x4, __half2* __restrict__ y2,
    int n, int E, int do_y) {
    __shared__ int lcnt[BNODES];
    __shared__ int lscan[BNODES];
    __shared__ int lcur[BNODES];
    __shared__ float sdinv[BNODES];
    __shared__ unsigned int sbuf[BCAP];
    int b = blockIdx.x, t = threadIdx.x;
    int node0 = b << BSHIFT;
    int nlocal = min(BNODES, n - node0);
    int base = bbase[b];
    int endp = bbase[b + 1];
    int cnt = endp - base;
    lcnt[t] = 0;
    __syncthreads();
    unsigned int er[BCAP / 256];
    #pragma unroll
    for (int k = 0; k < BCAP / 256; ++k) {
        int idx = k * 256 + t;
        er[k] = (idx < cnt) ? csr[base + idx] : 0xFFFFFFFFu;
        if (er[k] != 0xFFFFFFFFu) atomicAdd(&lcnt[er[k] & (BNODES - 1)], 1);
    }
    __syncthreads();
    int own = lcnt[t];
    sdinv[t] = rsqrtf((float)own + 1.0f);
    lscan[t] = own;
    __syncthreads();
    for (int off = 1; off < BNODES; off <<= 1) {
        int v = (t >= off) ? lscan[t - off] : 0;
        __syncthreads();
        lscan[t] += v;
        __syncthreads();
    }
    int excl = lscan[t] - own;
    lcur[t] = excl;
    if (t < nlocal) {
        row_ptr[node0 + t] = base + excl;
        dinv[node0 + t] = sdinv[t];
    }
    if (t == 0 && node0 + nlocal == n) row_ptr[n] = E;
    __syncthreads();
    #pragma unroll
    for (int k = 0; k < BCAP / 256; ++k) {
        unsigned int e = er[k];
        if (e != 0xFFFFFFFFu) {
            int p = atomicAdd(&lcur[(int)(e & (BNODES - 1))], 1);
            sbuf[p] = e >> 8;
        }
    }
    __syncthreads();
    for (int idx = t; idx < cnt; idx += 256) csr[base + idx] = sbuf[idx];
    if (do_y) {
        for (int i = t; i < nlocal * 16; i += 256) {
            int nl = i >> 4;
            int gi = (node0 + nl) * 16 + (i & 15);
            float di = sdinv[nl];
            float4 xv = x4[gi];
            y2[2 * gi]     = __floats2half2_rn(xv.x * di, xv.y * di);
            y2[2 * gi + 1] = __floats2half2_rn(xv.z * di, xv.w * di);
        }
    }
}

// Fused layer 1: block = 4 waves = 16 nodes (one MFMA tile).
// Gather phase interleaves the wave's 4 nodes: per lane up to 8 y-gathers +
// 8 csr prefetches in flight (was 2). Loop trips = max ceil(deg/16) over the
// 4 nodes (wave-uniform). f16 path only; f32 fallback keeps sequential loop.
__global__ __launch_bounds__(256) void fused1_kernel(
    const uint4* __restrict__ y, const float4* __restrict__ x4,
    const int* __restrict__ row_ptr, const int* __restrict__ csr,
    const float* __restrict__ dinv, const uint4* __restrict__ Wpk,
    const float* __restrict__ b1, const float* __restrict__ v,
    float* __restrict__ zz, int n) {
    __shared__ uint4 Atile[16 * 9];
    int t = threadIdx.x;
    int lane = t & 63;
    int wave = t >> 6;
    int node0 = blockIdx.x * 16;
    int q = lane >> 3, col = lane & 7;

    if (y) {
        int nodew = node0 + wave * 4;
        int rp[5];
        #pragma unroll
        for (int m = 0; m < 5; ++m) rp[m] = row_ptr[nodew + m];
        float f[4][8];
        #pragma unroll
        for (int m = 0; m < 4; ++m)
            #pragma unroll
            for (int r = 0; r < 8; ++r) f[m][r] = 0.f;
        // self rows (q==0 lanes carry them)
        if (q == 0) {
            #pragma unroll
            for (int m = 0; m < 4; ++m) {
                uint4 su = y[(nodew + m) * 8 + col];
                accum8(f[m], su);
            }
        }
        int pos[4], s0[4], s1[4];
        #pragma unroll
        for (int m = 0; m < 4; ++m) {
            pos[m] = rp[m];
            int p = pos[m] + q;
            s0[m] = (p < rp[m + 1]) ? csr[p] : -1;
            s1[m] = (p + 8 < rp[m + 1]) ? csr[p + 8] : -1;
        }
        while (true) {
            uint4 u0[4], u1[4];
            #pragma unroll
            for (int m = 0; m < 4; ++m) if (s0[m] >= 0) u0[m] = y[s0[m] * 8 + col];
            #pragma unroll
            for (int m = 0; m < 4; ++m) if (s1[m] >= 0) u1[m] = y[s1[m] * 8 + col];
            int n0[4], n1[4];
            #pragma unroll
            for (int m = 0; m < 4; ++m) {
                int np = pos[m] + 16 + q;
                n0[m] = (np < rp[m + 1]) ? csr[np] : -1;
                n1[m] = (np + 8 < rp[m + 1]) ? csr[np + 8] : -1;
            }
            #pragma unroll
            for (int m = 0; m < 4; ++m) {
                if (s0[m] >= 0) accum8(f[m], u0[m]);
                if (s1[m] >= 0) accum8(f[m], u1[m]);
            }
            bool more = false;
            #pragma unroll
            for (int m = 0; m < 4; ++m) {
                pos[m] += 16;
                more |= (pos[m] < rp[m + 1]);
                s0[m] = n0[m]; s1[m] = n1[m];
            }
            if (!more) break;
        }
        #pragma unroll
        for (int m = 0; m < 4; ++m) {
            #pragma unroll
            for (int off = 8; off < 64; off <<= 1) {
                #pragma unroll
                for (int r = 0; r < 8; ++r) f[m][r] += __shfl_xor(f[m][r], off, 64);
            }
            if (lane < 8) {
                float di = dinv[nodew + m];
                union { uint4 u; __half2 h[4]; } pk;
                #pragma unroll
                for (int r = 0; r < 4; ++r)
                    pk.h[r] = __floats2half2_rn(di * f[m][2 * r], di * f[m][2 * r + 1]);
                Atile[(wave * 4 + m) * 9 + lane] = pk.u;
            }
        }
    } else {
        // f32 fallback: sequential per-node gather with per-src weight dinv[s]
        #pragma unroll
        for (int j = 0; j < 4; ++j) {
            int m = wave * 4 + j;
            int node = node0 + m;
            float f[8];
            #pragma unroll
            for (int r = 0; r < 8; ++r) f[r] = 0.f;
            int beg = row_ptr[node], end = row_ptr[node + 1];
            if (q == 0) {
                float di0 = dinv[node];
                float4 a = x4[node * 16 + 2 * col];
                float4 b = x4[node * 16 + 2 * col + 1];
                f[0] = di0 * a.x; f[1] = di0 * a.y; f[2] = di0 * a.z; f[3] = di0 * a.w;
                f[4] = di0 * b.x; f[5] = di0 * b.y; f[6] = di0 * b.z; f[7] = di0 * b.w;
            }
            int p = beg + q;
            int s0 = (p < end) ? csr[p] : -1;
            int s1 = (p + 8 < end) ? csr[p + 8] : -1;
            for (int cb = beg; cb < end; cb += 16) {
                int c0 = s0, c1 = s1;
                int np = cb + 16 + q;
                s0 = (np < end) ? csr[np] : -1;
                s1 = (np + 8 < end) ? csr[np + 8] : -1;
                if (c0 >= 0) {
                    float w = dinv[c0];
                    float4 a = x4[c0 * 16 + 2 * col];
                    float4 b = x4[c0 * 16 + 2 * col + 1];
                    f[0] += w * a.x; f[1] += w * a.y; f[2] += w * a.z; f[3] += w * a.w;
                    f[4] += w * b.x; f[5] += w * b.y; f[6] += w * b.z; f[7] += w * b.w;
                }
                if (c1 >= 0) {
                    float w = dinv[c1];
                    float4 a = x4[c1 * 16 + 2 * col];
                    float4 b = x4[c1 * 16 + 2 * col + 1];
                    f[0] += w * a.x; f[1] += w * a.y; f[2] += w * a.z; f[3] += w * a.w;
                    f[4] += w * b.x; f[5] += w * b.y; f[6] += w * b.z; f[7] += w * b.w;
                }
            }
            #pragma unroll
            for (int off = 8; off < 64; off <<= 1) {
                #pragma unroll
                for (int r = 0; r < 8; ++r) f[r] += __shfl_xor(f[r], off, 64);
            }
            if (lane < 8) {
                float di = dinv[node];
                union { uint4 u; __half2 h[4]; } pk;
                #pragma unroll
                for (int r = 0; r < 4; ++r)
                    pk.h[r] = __floats2half2_rn(di * f[2 * r], di * f[2 * r + 1]);
                Atile[m * 9 + lane] = pk.u;
            }
        }
    }
    __syncthreads();
    if (t >= 64) return;

    int mm = lane & 15, kq = lane >> 4;
    half8 A0 = as_half8(Atile[mm * 9 + kq]);
    half8 A1 = as_half8(Atile[mm * 9 + 4 + kq]);
    f32x4 acc[8];
    #pragma unroll
    for (int cb = 0; cb < 8; ++cb) acc[cb] = (f32x4){0.f, 0.f, 0.f, 0.f};
    #pragma unroll
    for (int cb = 0; cb < 8; ++cb) {
        half8 bh0 = as_half8(Wpk[(cb * 2 + 0) * 64 + lane]);
        half8 bh1 = as_half8(Wpk[(cb * 2 + 1) * 64 + lane]);
        half8 bl0 = as_half8(Wpk[1024 + (cb * 2 + 0) * 64 + lane]);
        half8 bl1 = as_half8(Wpk[1024 + (cb * 2 + 1) * 64 + lane]);
        acc[cb] = __builtin_amdgcn_mfma_f32_16x16x32_f16(A0, bh0, acc[cb], 0, 0, 0);
        acc[cb] = __builtin_amdgcn_mfma_f32_16x16x32_f16(A1, bh1, acc[cb], 0, 0, 0);
        acc[cb] = __builtin_amdgcn_mfma_f32_16x16x32_f16(A0, bl0, acc[cb], 0, 0, 0);
        acc[cb] = __builtin_amdgcn_mfma_f32_16x16x32_f16(A1, bl1, acc[cb], 0, 0, 0);
    }
    float zp[4] = {0.f, 0.f, 0.f, 0.f};
    #pragma unroll
    for (int cb = 0; cb < 8; ++cb) {
        int colg = cb * 16 + mm;
        float bb = b1[colg], vv = v[colg];
        #pragma unroll
        for (int r = 0; r < 4; ++r) {
            float h = acc[cb][r] + bb;
            h = fmaxf(h, 0.f);
            zp[r] += h * vv;
        }
    }
    #pragma unroll
    for (int off = 1; off < 16; off <<= 1) {
        #pragma unroll
        for (int r = 0; r < 4; ++r) zp[r] += __shfl_xor(zp[r], off, 64);
    }
    if (mm == 0) {
        int nb = node0 + kq * 4;
        #pragma unroll
        for (int r = 0; r < 4; ++r) zz[nb + r] = dinv[nb + r] * zp[r];
    }
}

// Layer 2 (collapsed): out[i] = c + dinv[i]*(zz[i] + sum_in zz[s]). 16 lanes/node.
__global__ void out_kernel(const int* __restrict__ row_ptr, const int* __restrict__ csr,
                           const float* __restrict__ dinv, const float* __restrict__ zz,
                           const float* __restrict__ c, float* __restrict__ out, int n) {
    int tid = blockIdx.x * blockDim.x + threadIdx.x;
    int node = tid >> 4;
    int sub = tid & 15;
    if (node >= n) return;
    int beg = row_ptr[node], end = row_ptr[node + 1];
    float acc = 0.f;
    for (int e = beg + sub; e < end; e += 16) acc += zz[csr[e]];
    acc += __shfl_xor(acc, 1, 64);
    acc += __shfl_xor(acc, 2, 64);
    acc += __shfl_xor(acc, 4, 64);
    acc += __shfl_xor(acc, 8, 64);
    if (sub == 0) out[node] = c[0] + dinv[node] * (acc + zz[node]);
}

extern "C" void kernel_launch(void* const* d_in, const int* in_sizes, int n_in,
                              void* d_out, int out_size, void* d_ws, size_t ws_size,
                              hipStream_t stream) {
    const float* x  = (const float*)d_in[0];
    const int*   ei = (const int*)d_in[1];
    const float* W1 = (const float*)d_in[2];
    const float* b1 = (const float*)d_in[3];
    const float* W2 = (const float*)d_in[4];
    const float* b2 = (const float*)d_in[5];
    const float* Wl = (const float*)d_in[6];
    const float* bl = (const float*)d_in[7];
    float* out = (float*)d_out;

    int E = in_sizes[1] / 2;
    const int* src = ei;
    const int* dst = ei + E;
    int Epad = (E + 3) & ~3;

    float* ws      = (float*)d_ws;
    float* dinv    = ws;                       // N
    int*   row_ptr = (int*)(ws + N_NODES);     // N+4
    float* zz      = (float*)(row_ptr + N_NODES + 4);  // N
    float* v       = zz + N_NODES;             // 128
    float* c       = v + HID;                  // 4
    int*   bbase   = (int*)(c + 4);            // 512
    int*   bcur    = bbase + 512;              // 512
    int*   csr     = bcur + 512;               // Epad (bmat overlays: 391*392 ints << E)
    int*   bmat    = csr;                      // overlay: used only before partA
    uint4* Wpk     = (uint4*)(csr + Epad);     // 2048 uint4 (32 KB)
    __half* y      = (__half*)((float*)Wpk + 8192);  // N*64 halves

    size_t base_floats = (size_t)N_NODES * 3 + 4 + 128 + 4 + 1024 + (size_t)Epad + 8192;
    size_t need_f16 = (base_floats + (size_t)N_NODES * 32) * 4;
    bool use_f16 = (ws_size >= need_f16);

    int nchunks = (E + ACHUNK - 1) / ACHUNK;   // 391

    prep_kernel<<<9, 256, 0, stream>>>(W1, W2, b2, Wl, bl, v, c, Wpk);
    bhist_kernel<<<nchunks, 256, 0, stream>>>(dst, bmat, E);
    bscan_kernel<<<1, 512, 0, stream>>>(bmat, bbase, bcur, nchunks, E);
    partA_kernel<<<nchunks, 256, 0, stream>>>(src, dst, bcur, (unsigned int*)csr, E);
    partB_kernel<<<NBUCKETS, 256, 0, stream>>>(
        bbase, (unsigned int*)csr, row_ptr, dinv,
        (const float4*)x, (__half2*)y, N_NODES, E, use_f16 ? 1 : 0);
    fused1_kernel<<<N_NODES / 16, 256, 0, stream>>>(
        use_f16 ? (const uint4*)y : nullptr, (const float4*)x,
        row_ptr, csr, dinv, Wpk, b1, v, zz, N_NODES);
    out_kernel<<<(N_NODES * 16 + 255) / 256, 256, 0, stream>>>(
        row_ptr, csr, dinv, zz, c, out, N_NODES);
}

// Round 12
// 218.898 us; speedup vs baseline: 3.6939x; 1.1757x over previous
//
#include <hip/hip_runtime.h>
#include <hip/hip_fp16.h>

// GCN 2-layer, N=100000, F=64, H=128, O=100, out [N,1] fp32.
// out = agg(relu(agg(x)@W1 + b1) . (W2@Wl)) + (b2@Wl + bl)
// agg via CSR-by-dst GATHER; layer-1 GEMV via MFMA (fp16 hi+lo split W1).
// CSR built bucket-wise (bhist -> breduce/bscan -> partA multi-split ->
// partB sort). fused1 gather interleaves 4 nodes for 4x MLP.

#define N_NODES 100000
#define F_IN 64
#define HID 128
#define OUT2 100
#define BSHIFT 8
#define BNODES 256
#define NBUCKETS ((N_NODES + BNODES - 1) / BNODES)  // 391
#define BCAP 9216   // partB LDS staging cap (bucket mean 4096, sigma ~64)
#define ACHUNK 4096 // edges per block in bhist/partA
#define NB_PAD 512
#define BMROW 392   // bmat row stride (ints)
#define RROWS 16    // rows per breduce block
#define SENTB 0xFFFFu

typedef _Float16 half8 __attribute__((ext_vector_type(8)));
typedef float f32x4 __attribute__((ext_vector_type(4)));

static __device__ __forceinline__ half8 as_half8(uint4 u) {
    union { uint4 u; half8 h; } x; x.u = u; return x.h;
}

static __device__ __forceinline__ void accum8(float* f, uint4 u) {
    const __half2* hp = (const __half2*)&u;
    #pragma unroll
    for (int r = 0; r < 4; ++r) {
        float2 fv = __half22float2(hp[r]);
        f[2 * r] += fv.x; f[2 * r + 1] += fv.y;
    }
}

// Per-chunk bucket histogram: zero global atomics. bmat[chunk][bin].
__global__ __launch_bounds__(256) void bhist_kernel(
    const int* __restrict__ dst, int* __restrict__ bmat, int E) {
    __shared__ int hist[BMROW];
    int t = threadIdx.x;
    hist[t] = 0;
    if (t + 256 < BMROW) hist[t + 256] = 0;
    __syncthreads();
    int base = blockIdx.x * ACHUNK;
    #pragma unroll
    for (int k = 0; k < 16; ++k) {
        int e = base + k * 256 + t;
        if (e < E) atomicAdd(&hist[dst[e] >> BSHIFT], 1);
    }
    __syncthreads();
    int* row = bmat + blockIdx.x * BMROW;
    row[t] = hist[t];
    if (t + 256 < BMROW) row[t + 256] = hist[t + 256];
}

// Parallel column-reduce of bmat: each block sums RROWS rows; one atomic
// per bin per block into gcnt (chain depth = nblocks = 25, negligible).
__global__ __launch_bounds__(256) void breduce_kernel(
    const int* __restrict__ bmat, int* __restrict__ gcnt, int nchunks) {
    int t = threadIdx.x;
    int r0 = blockIdx.x * RROWS;
    int rend = min(r0 + RROWS, nchunks);
    #pragma unroll
    for (int h = 0; h < 2; ++h) {
        int bin = t + h * 256;
        if (bin < BMROW) {
            int acc = 0;
            for (int r = r0; r < rend; ++r) acc += bmat[r * BMROW + bin];
            if (acc) atomicAdd(&gcnt[bin], acc);
        }
    }
}

// Single block: scan gcnt -> bucket bases/cursors. Tiny now.
__global__ __launch_bounds__(512) void bscan_kernel(
    const int* __restrict__ gcnt, int* __restrict__ bbase, int* __restrict__ bcur, int E) {
    __shared__ int ls[512];
    int t = threadIdx.x;
    int acc = (t < NBUCKETS) ? gcnt[t] : 0;
    ls[t] = acc;
    __syncthreads();
    for (int off = 1; off < 512; off <<= 1) {
        int v = (t >= off) ? ls[t - off] : 0;
        __syncthreads();
        ls[t] += v;
        __syncthreads();
    }
    int excl = ls[t] - acc;
    if (t < NBUCKETS) { bbase[t] = excl; bcur[t] = excl; }
    if (t == NBUCKETS - 1) bbase[NBUCKETS] = excl + acc;  // = E
}

// Blocks 0..7: pack W1 into MFMA B-fragment layout, fp16 hi+lo split.
// Block 8: v = W2@Wl (t<128), c = b2.Wl + bl (t==128).
__global__ __launch_bounds__(256) void prep_kernel(
    const float* __restrict__ W1, const float* __restrict__ W2,
    const float* __restrict__ b2, const float* __restrict__ Wl,
    const float* __restrict__ bl,
    float* __restrict__ v, float* __restrict__ c, uint4* __restrict__ Wpk) {
    int t = threadIdx.x;
    if (blockIdx.x < 8) {
        // idx: bit10 = part (0=hi,1=lo), bits9..7 = cb, bit6 = kf, bits5..0 = lane
        int idx = blockIdx.x * 256 + t;
        int lane2 = idx & 63;
        int kf    = (idx >> 6) & 1;
        int cb    = (idx >> 7) & 7;
        int part  = (idx >> 10) & 1;
        union { uint4 u; unsigned short s[8]; } pk;
        #pragma unroll
        for (int j = 0; j < 8; ++j) {
            int k    = kf * 32 + (lane2 >> 4) * 8 + j;
            int colg = cb * 16 + (lane2 & 15);
            float w = W1[k * HID + colg];
            __half h = __float2half_rn(w);
            if (part) h = __float2half_rn(w - __half2float(h));
            pk.s[j] = __half_as_ushort(h);
        }
        Wpk[idx] = pk.u;
    } else {
        if (t < HID) {
            float acc = 0.f;
            for (int k = 0; k < OUT2; ++k) acc += W2[t * OUT2 + k] * Wl[k];
            v[t] = acc;
        } else if (t == HID) {
            float acc = bl[0];
            for (int k = 0; k < OUT2; ++k) acc += b2[k] * Wl[k];
            *c = acc;
        }
    }
}

// Pass A: LDS multi-split into dst-buckets; ONE reserve-atomic per bucket
// per block. Packed entry = (src<<8) | (dst&255).
__global__ __launch_bounds__(256) void partA_kernel(
    const int* __restrict__ src, const int* __restrict__ dst,
    int* __restrict__ bcur, unsigned int* __restrict__ ebuf, int E) {
    __shared__ unsigned int stage[ACHUNK];       // 16 KB
    __shared__ unsigned short sb[ACHUNK];        // 8 KB
    __shared__ int hist[NB_PAD];
    __shared__ int ocnt[NB_PAD];
    __shared__ int gbase[NB_PAD];
    __shared__ int cnt2[NB_PAD];
    int t = threadIdx.x;
    int base = blockIdx.x * ACHUNK;
    int total = E - base; if (total > ACHUNK) total = ACHUNK;

    hist[t] = 0; hist[t + 256] = 0;
    cnt2[t] = 0; cnt2[t + 256] = 0;
    __syncthreads();

    unsigned int pe[16];
    unsigned short bk[16];
    #pragma unroll
    for (int k = 0; k < 16; ++k) {
        int e = base + k * 256 + t;
        if (e < E) {
            int s = src[e], d = dst[e];
            pe[k] = ((unsigned int)s << 8) | (unsigned int)(d & (BNODES - 1));
            bk[k] = (unsigned short)(d >> BSHIFT);
            atomicAdd(&hist[bk[k]], 1);
        } else {
            bk[k] = SENTB;
        }
    }
    __syncthreads();
    ocnt[t] = hist[t]; ocnt[t + 256] = hist[t + 256];
    __syncthreads();
    for (int off = 1; off < NB_PAD; off <<= 1) {
        int v0 = (t >= off) ? hist[t - off] : 0;
        int v1 = hist[t + 256 - off];
        __syncthreads();
        hist[t] += v0; hist[t + 256] += v1;
        __syncthreads();
    }
    #pragma unroll
    for (int i = 0; i < 2; ++i) {
        int b = (t + i * 256 + blockIdx.x * 131) & (NB_PAD - 1);
        int cc = ocnt[b];
        if (cc > 0 && b < NBUCKETS) gbase[b] = atomicAdd(&bcur[b], cc);
    }
    __syncthreads();
    #pragma unroll
    for (int k = 0; k < 16; ++k) {
        if (bk[k] != SENTB) {
            int b = bk[k];
            int pos = (hist[b] - ocnt[b]) + atomicAdd(&cnt2[b], 1);
            stage[pos] = pe[k];
            sb[pos] = (unsigned short)b;
        }
    }
    __syncthreads();
    #pragma unroll
    for (int k = 0; k < 16; ++k) {
        int idx = k * 256 + t;
        if (idx < total) {
            int b = sb[idx];
            int lo = hist[b] - ocnt[b];
            ebuf[gbase[b] + (idx - lo)] = stage[idx];
        }
    }
}

// Pass B: one block per bucket, in-place counting sort; ALSO emits
// row_ptr + dinv for its 256 nodes and the fp16 pre-scaled y rows.
__global__ __launch_bounds__(256) void partB_kernel(
    const int* __restrict__ bbase, unsigned int* __restrict__ csr,
    int* __restrict__ row_ptr, float* __restrict__ dinv,
    const float4* __restrict__ x4, __half2* __restrict__ y2,
    int n, int E, int do_y) {
    __shared__ int lcnt[BNODES];
    __shared__ int lscan[BNODES];
    __shared__ int lcur[BNODES];
    __shared__ float sdinv[BNODES];
    __shared__ unsigned int sbuf[BCAP];
    int b = blockIdx.x, t = threadIdx.x;
    int node0 = b << BSHIFT;
    int nlocal = min(BNODES, n - node0);
    int base = bbase[b];
    int endp = bbase[b + 1];
    int cnt = endp - base;
    lcnt[t] = 0;
    __syncthreads();
    unsigned int er[BCAP / 256];
    #pragma unroll
    for (int k = 0; k < BCAP / 256; ++k) {
        int idx = k * 256 + t;
        er[k] = (idx < cnt) ? csr[base + idx] : 0xFFFFFFFFu;
        if (er[k] != 0xFFFFFFFFu) atomicAdd(&lcnt[er[k] & (BNODES - 1)], 1);
    }
    __syncthreads();
    int own = lcnt[t];
    sdinv[t] = rsqrtf((float)own + 1.0f);
    lscan[t] = own;
    __syncthreads();
    for (int off = 1; off < BNODES; off <<= 1) {
        int v = (t >= off) ? lscan[t - off] : 0;
        __syncthreads();
        lscan[t] += v;
        __syncthreads();
    }
    int excl = lscan[t] - own;
    lcur[t] = excl;
    if (t < nlocal) {
        row_ptr[node0 + t] = base + excl;
        dinv[node0 + t] = sdinv[t];
    }
    if (t == 0 && node0 + nlocal == n) row_ptr[n] = E;
    __syncthreads();
    #pragma unroll
    for (int k = 0; k < BCAP / 256; ++k) {
        unsigned int e = er[k];
        if (e != 0xFFFFFFFFu) {
            int p = atomicAdd(&lcur[(int)(e & (BNODES - 1))], 1);
            sbuf[p] = e >> 8;
        }
    }
    __syncthreads();
    for (int idx = t; idx < cnt; idx += 256) csr[base + idx] = sbuf[idx];
    if (do_y) {
        for (int i = t; i < nlocal * 16; i += 256) {
            int nl = i >> 4;
            int gi = (node0 + nl) * 16 + (i & 15);
            float di = sdinv[nl];
            float4 xv = x4[gi];
            y2[2 * gi]     = __floats2half2_rn(xv.x * di, xv.y * di);
            y2[2 * gi + 1] = __floats2half2_rn(xv.z * di, xv.w * di);
        }
    }
}

// Fused layer 1: block = 4 waves = 16 nodes (one MFMA tile).
// Gather phase interleaves the wave's 4 nodes (up to 8 y-gathers in flight).
__global__ __launch_bounds__(256) void fused1_kernel(
    const uint4* __restrict__ y, const float4* __restrict__ x4,
    const int* __restrict__ row_ptr, const int* __restrict__ csr,
    const float* __restrict__ dinv, const uint4* __restrict__ Wpk,
    const float* __restrict__ b1, const float* __restrict__ v,
    float* __restrict__ zz, int n) {
    __shared__ uint4 Atile[16 * 9];
    int t = threadIdx.x;
    int lane = t & 63;
    int wave = t >> 6;
    int node0 = blockIdx.x * 16;
    int q = lane >> 3, col = lane & 7;

    if (y) {
        int nodew = node0 + wave * 4;
        int rp[5];
        #pragma unroll
        for (int m = 0; m < 5; ++m) rp[m] = row_ptr[nodew + m];
        float f[4][8];
        #pragma unroll
        for (int m = 0; m < 4; ++m)
            #pragma unroll
            for (int r = 0; r < 8; ++r) f[m][r] = 0.f;
        if (q == 0) {
            #pragma unroll
            for (int m = 0; m < 4; ++m) {
                uint4 su = y[(nodew + m) * 8 + col];
                accum8(f[m], su);
            }
        }
        int pos[4], s0[4], s1[4];
        #pragma unroll
        for (int m = 0; m < 4; ++m) {
            pos[m] = rp[m];
            int p = pos[m] + q;
            s0[m] = (p < rp[m + 1]) ? csr[p] : -1;
            s1[m] = (p + 8 < rp[m + 1]) ? csr[p + 8] : -1;
        }
        while (true) {
            uint4 u0[4], u1[4];
            #pragma unroll
            for (int m = 0; m < 4; ++m) if (s0[m] >= 0) u0[m] = y[s0[m] * 8 + col];
            #pragma unroll
            for (int m = 0; m < 4; ++m) if (s1[m] >= 0) u1[m] = y[s1[m] * 8 + col];
            int n0[4], n1[4];
            #pragma unroll
            for (int m = 0; m < 4; ++m) {
                int np = pos[m] + 16 + q;
                n0[m] = (np < rp[m + 1]) ? csr[np] : -1;
                n1[m] = (np + 8 < rp[m + 1]) ? csr[np + 8] : -1;
            }
            #pragma unroll
            for (int m = 0; m < 4; ++m) {
                if (s0[m] >= 0) accum8(f[m], u0[m]);
                if (s1[m] >= 0) accum8(f[m], u1[m]);
            }
            bool more = false;
            #pragma unroll
            for (int m = 0; m < 4; ++m) {
                pos[m] += 16;
                more |= (pos[m] < rp[m + 1]);
                s0[m] = n0[m]; s1[m] = n1[m];
            }
            if (!more) break;
        }
        #pragma unroll
        for (int m = 0; m < 4; ++m) {
            #pragma unroll
            for (int off = 8; off < 64; off <<= 1) {
                #pragma unroll
                for (int r = 0; r < 8; ++r) f[m][r] += __shfl_xor(f[m][r], off, 64);
            }
            if (lane < 8) {
                float di = dinv[nodew + m];
                union { uint4 u; __half2 h[4]; } pk;
                #pragma unroll
                for (int r = 0; r < 4; ++r)
                    pk.h[r] = __floats2half2_rn(di * f[m][2 * r], di * f[m][2 * r + 1]);
                Atile[(wave * 4 + m) * 9 + lane] = pk.u;
            }
        }
    } else {
        // f32 fallback: sequential per-node gather with per-src weight dinv[s]
        #pragma unroll
        for (int j = 0; j < 4; ++j) {
            int m = wave * 4 + j;
            int node = node0 + m;
            float f[8];
            #pragma unroll
            for (int r = 0; r < 8; ++r) f[r] = 0.f;
            int beg = row_ptr[node], end = row_ptr[node + 1];
            if (q == 0) {
                float di0 = dinv[node];
                float4 a = x4[node * 16 + 2 * col];
                float4 b = x4[node * 16 + 2 * col + 1];
                f[0] = di0 * a.x; f[1] = di0 * a.y; f[2] = di0 * a.z; f[3] = di0 * a.w;
                f[4] = di0 * b.x; f[5] = di0 * b.y; f[6] = di0 * b.z; f[7] = di0 * b.w;
            }
            int p = beg + q;
            int s0 = (p < end) ? csr[p] : -1;
            int s1 = (p + 8 < end) ? csr[p + 8] : -1;
            for (int cb = beg; cb < end; cb += 16) {
                int c0 = s0, c1 = s1;
                int np = cb + 16 + q;
                s0 = (np < end) ? csr[np] : -1;
                s1 = (np + 8 < end) ? csr[np + 8] : -1;
                if (c0 >= 0) {
                    float w = dinv[c0];
                    float4 a = x4[c0 * 16 + 2 * col];
                    float4 b = x4[c0 * 16 + 2 * col + 1];
                    f[0] += w * a.x; f[1] += w * a.y; f[2] += w * a.z; f[3] += w * a.w;
                    f[4] += w * b.x; f[5] += w * b.y; f[6] += w * b.z; f[7] += w * b.w;
                }
                if (c1 >= 0) {
                    float w = dinv[c1];
                    float4 a = x4[c1 * 16 + 2 * col];
                    float4 b = x4[c1 * 16 + 2 * col + 1];
                    f[0] += w * a.x; f[1] += w * a.y; f[2] += w * a.z; f[3] += w * a.w;
                    f[4] += w * b.x; f[5] += w * b.y; f[6] += w * b.z; f[7] += w * b.w;
                }
            }
            #pragma unroll
            for (int off = 8; off < 64; off <<= 1) {
                #pragma unroll
                for (int r = 0; r < 8; ++r) f[r] += __shfl_xor(f[r], off, 64);
            }
            if (lane < 8) {
                float di = dinv[node];
                union { uint4 u; __half2 h[4]; } pk;
                #pragma unroll
                for (int r = 0; r < 4; ++r)
                    pk.h[r] = __floats2half2_rn(di * f[2 * r], di * f[2 * r + 1]);
                Atile[m * 9 + lane] = pk.u;
            }
        }
    }
    __syncthreads();
    if (t >= 64) return;

    int mm = lane & 15, kq = lane >> 4;
    half8 A0 = as_half8(Atile[mm * 9 + kq]);
    half8 A1 = as_half8(Atile[mm * 9 + 4 + kq]);
    f32x4 acc[8];
    #pragma unroll
    for (int cb = 0; cb < 8; ++cb) acc[cb] = (f32x4){0.f, 0.f, 0.f, 0.f};
    #pragma unroll
    for (int cb = 0; cb < 8; ++cb) {
        half8 bh0 = as_half8(Wpk[(cb * 2 + 0) * 64 + lane]);
        half8 bh1 = as_half8(Wpk[(cb * 2 + 1) * 64 + lane]);
        half8 bl0 = as_half8(Wpk[1024 + (cb * 2 + 0) * 64 + lane]);
        half8 bl1 = as_half8(Wpk[1024 + (cb * 2 + 1) * 64 + lane]);
        acc[cb] = __builtin_amdgcn_mfma_f32_16x16x32_f16(A0, bh0, acc[cb], 0, 0, 0);
        acc[cb] = __builtin_amdgcn_mfma_f32_16x16x32_f16(A1, bh1, acc[cb], 0, 0, 0);
        acc[cb] = __builtin_amdgcn_mfma_f32_16x16x32_f16(A0, bl0, acc[cb], 0, 0, 0);
        acc[cb] = __builtin_amdgcn_mfma_f32_16x16x32_f16(A1, bl1, acc[cb], 0, 0, 0);
    }
    float zp[4] = {0.f, 0.f, 0.f, 0.f};
    #pragma unroll
    for (int cb = 0; cb < 8; ++cb) {
        int colg = cb * 16 + mm;
        float bb = b1[colg], vv = v[colg];
        #pragma unroll
        for (int r = 0; r < 4; ++r) {
            float h = acc[cb][r] + bb;
            h = fmaxf(h, 0.f);
            zp[r] += h * vv;
        }
    }
    #pragma unroll
    for (int off = 1; off < 16; off <<= 1) {
        #pragma unroll
        for (int r = 0; r < 4; ++r) zp[r] += __shfl_xor(zp[r], off, 64);
    }
    if (mm == 0) {
        int nb = node0 + kq * 4;
        #pragma unroll
        for (int r = 0; r < 4; ++r) zz[nb + r] = dinv[nb + r] * zp[r];
    }
}

// Layer 2 (collapsed): out[i] = c + dinv[i]*(zz[i] + sum_in zz[s]). 16 lanes/node.
__global__ void out_kernel(const int* __restrict__ row_ptr, const int* __restrict__ csr,
                           const float* __restrict__ dinv, const float* __restrict__ zz,
                           const float* __restrict__ c, float* __restrict__ out, int n) {
    int tid = blockIdx.x * blockDim.x + threadIdx.x;
    int node = tid >> 4;
    int sub = tid & 15;
    if (node >= n) return;
    int beg = row_ptr[node], end = row_ptr[node + 1];
    float acc = 0.f;
    for (int e = beg + sub; e < end; e += 16) acc += zz[csr[e]];
    acc += __shfl_xor(acc, 1, 64);
    acc += __shfl_xor(acc, 2, 64);
    acc += __shfl_xor(acc, 4, 64);
    acc += __shfl_xor(acc, 8, 64);
    if (sub == 0) out[node] = c[0] + dinv[node] * (acc + zz[node]);
}

extern "C" void kernel_launch(void* const* d_in, const int* in_sizes, int n_in,
                              void* d_out, int out_size, void* d_ws, size_t ws_size,
                              hipStream_t stream) {
    const float* x  = (const float*)d_in[0];
    const int*   ei = (const int*)d_in[1];
    const float* W1 = (const float*)d_in[2];
    const float* b1 = (const float*)d_in[3];
    const float* W2 = (const float*)d_in[4];
    const float* b2 = (const float*)d_in[5];
    const float* Wl = (const float*)d_in[6];
    const float* bl = (const float*)d_in[7];
    float* out = (float*)d_out;

    int E = in_sizes[1] / 2;
    const int* src = ei;
    const int* dst = ei + E;
    int Epad = (E + 3) & ~3;

    float* ws      = (float*)d_ws;
    float* dinv    = ws;                       // N
    int*   row_ptr = (int*)(ws + N_NODES);     // N+4
    float* zz      = (float*)(row_ptr + N_NODES + 4);  // N
    float* v       = zz + N_NODES;             // 128
    float* c       = v + HID;                  // 4
    int*   bbase   = (int*)(c + 4);            // 512
    int*   bcur    = bbase + 512;              // 512
    int*   gcnt    = bcur + 512;               // 512
    int*   csr     = gcnt + 512;               // Epad (bmat overlays)
    int*   bmat    = csr;                      // overlay: used only before partA
    uint4* Wpk     = (uint4*)(csr + Epad);     // 2048 uint4 (32 KB)
    __half* y      = (__half*)((float*)Wpk + 8192);  // N*64 halves

    size_t base_floats = (size_t)N_NODES * 3 + 4 + 128 + 4 + 1536 + (size_t)Epad + 8192;
    size_t need_f16 = (base_floats + (size_t)N_NODES * 32) * 4;
    bool use_f16 = (ws_size >= need_f16);

    int nchunks = (E + ACHUNK - 1) / ACHUNK;   // 391
    int nred = (nchunks + RROWS - 1) / RROWS;  // 25

    hipMemsetAsync(gcnt, 0, sizeof(int) * 512, stream);
    prep_kernel<<<9, 256, 0, stream>>>(W1, W2, b2, Wl, bl, v, c, Wpk);
    bhist_kernel<<<nchunks, 256, 0, stream>>>(dst, bmat, E);
    breduce_kernel<<<nred, 256, 0, stream>>>(bmat, gcnt, nchunks);
    bscan_kernel<<<1, 512, 0, stream>>>(gcnt, bbase, bcur, E);
    partA_kernel<<<nchunks, 256, 0, stream>>>(src, dst, bcur, (unsigned int*)csr, E);
    partB_kernel<<<NBUCKETS, 256, 0, stream>>>(
        bbase, (unsigned int*)csr, row_ptr, dinv,
        (const float4*)x, (__half2*)y, N_NODES, E, use_f16 ? 1 : 0);
    fused1_kernel<<<N_NODES / 16, 256, 0, stream>>>(
        use_f16 ? (const uint4*)y : nullptr, (const float4*)x,
        row_ptr, csr, dinv, Wpk, b1, v, zz, N_NODES);
    out_kernel<<<(N_NODES * 16 + 255) / 256, 256, 0, stream>>>(
        row_ptr, csr, dinv, zz, c, out, N_NODES);
}

// Round 13
// 207.760 us; speedup vs baseline: 3.8920x; 1.0536x over previous
//
#include <hip/hip_runtime.h>
#include <hip/hip_fp16.h>

// GCN 2-layer, N=100000, F=64, H=128, O=100, out [N,1] fp32.
// out = agg(relu(agg(x)@W1 + b1) . (W2@Wl)) + (b2@Wl + bl)
// agg via CSR-by-dst GATHER; layer-1 GEMV via MFMA (fp16 hi+lo split W1).
// CSR built bucket-wise (prep_hist -> breduce/bscan -> partA multi-split ->
// partB sort). fused1 gather interleaves 4 nodes; out pipelines 2 slots/lane.

#define N_NODES 100000
#define F_IN 64
#define HID 128
#define OUT2 100
#define BSHIFT 8
#define BNODES 256
#define NBUCKETS ((N_NODES + BNODES - 1) / BNODES)  // 391
#define BCAP 9216   // partB LDS staging cap (bucket mean 4096, sigma ~64)
#define ACHUNK 4096 // edges per block in bhist/partA
#define NB_PAD 512
#define BMROW 392   // bmat row stride (ints)
#define RROWS 16    // rows per breduce block
#define SENTB 0xFFFFu

typedef _Float16 half8 __attribute__((ext_vector_type(8)));
typedef float f32x4 __attribute__((ext_vector_type(4)));

static __device__ __forceinline__ half8 as_half8(uint4 u) {
    union { uint4 u; half8 h; } x; x.u = u; return x.h;
}

static __device__ __forceinline__ void accum8(float* f, uint4 u) {
    const __half2* hp = (const __half2*)&u;
    #pragma unroll
    for (int r = 0; r < 4; ++r) {
        float2 fv = __half22float2(hp[r]);
        f[2 * r] += fv.x; f[2 * r + 1] += fv.y;
    }
}

// Blocks 0..7: pack W1 (MFMA B-layout, fp16 hi+lo). Block 8: v/c + zero gcnt.
// Blocks 9..: per-chunk bucket histogram (LDS, zero global atomics).
__global__ __launch_bounds__(256) void prep_hist_kernel(
    const float* __restrict__ W1, const float* __restrict__ W2,
    const float* __restrict__ b2, const float* __restrict__ Wl,
    const float* __restrict__ bl,
    float* __restrict__ v, float* __restrict__ c, uint4* __restrict__ Wpk,
    int* __restrict__ gcnt,
    const int* __restrict__ dst, int* __restrict__ bmat, int E) {
    __shared__ int hist[BMROW];
    int t = threadIdx.x;
    if (blockIdx.x < 8) {
        // idx: bit10 = part (0=hi,1=lo), bits9..7 = cb, bit6 = kf, bits5..0 = lane
        int idx = blockIdx.x * 256 + t;
        int lane2 = idx & 63;
        int kf    = (idx >> 6) & 1;
        int cb    = (idx >> 7) & 7;
        int part  = (idx >> 10) & 1;
        union { uint4 u; unsigned short s[8]; } pk;
        #pragma unroll
        for (int j = 0; j < 8; ++j) {
            int k    = kf * 32 + (lane2 >> 4) * 8 + j;
            int colg = cb * 16 + (lane2 & 15);
            float w = W1[k * HID + colg];
            __half h = __float2half_rn(w);
            if (part) h = __float2half_rn(w - __half2float(h));
            pk.s[j] = __half_as_ushort(h);
        }
        Wpk[idx] = pk.u;
    } else if (blockIdx.x == 8) {
        gcnt[t] = 0; gcnt[t + 256] = 0;
        if (t < HID) {
            float acc = 0.f;
            for (int k = 0; k < OUT2; ++k) acc += W2[t * OUT2 + k] * Wl[k];
            v[t] = acc;
        } else if (t == HID) {
            float acc = bl[0];
            for (int k = 0; k < OUT2; ++k) acc += b2[k] * Wl[k];
            *c = acc;
        }
    } else {
        int chunk = blockIdx.x - 9;
        hist[t] = 0;
        if (t + 256 < BMROW) hist[t + 256] = 0;
        __syncthreads();
        int base = chunk * ACHUNK;
        #pragma unroll
        for (int k = 0; k < 16; ++k) {
            int e = base + k * 256 + t;
            if (e < E) atomicAdd(&hist[dst[e] >> BSHIFT], 1);
        }
        __syncthreads();
        int* row = bmat + chunk * BMROW;
        row[t] = hist[t];
        if (t + 256 < BMROW) row[t + 256] = hist[t + 256];
    }
}

// Parallel column-reduce of bmat: each block sums RROWS rows; one atomic
// per bin per block into gcnt (chain depth = nblocks = 25, negligible).
__global__ __launch_bounds__(256) void breduce_kernel(
    const int* __restrict__ bmat, int* __restrict__ gcnt, int nchunks) {
    int t = threadIdx.x;
    int r0 = blockIdx.x * RROWS;
    int rend = min(r0 + RROWS, nchunks);
    #pragma unroll
    for (int h = 0; h < 2; ++h) {
        int bin = t + h * 256;
        if (bin < BMROW) {
            int acc = 0;
            for (int r = r0; r < rend; ++r) acc += bmat[r * BMROW + bin];
            if (acc) atomicAdd(&gcnt[bin], acc);
        }
    }
}

// Single block: scan gcnt -> bucket bases/cursors.
__global__ __launch_bounds__(512) void bscan_kernel(
    const int* __restrict__ gcnt, int* __restrict__ bbase, int* __restrict__ bcur, int E) {
    __shared__ int ls[512];
    int t = threadIdx.x;
    int acc = (t < NBUCKETS) ? gcnt[t] : 0;
    ls[t] = acc;
    __syncthreads();
    for (int off = 1; off < 512; off <<= 1) {
        int v = (t >= off) ? ls[t - off] : 0;
        __syncthreads();
        ls[t] += v;
        __syncthreads();
    }
    int excl = ls[t] - acc;
    if (t < NBUCKETS) { bbase[t] = excl; bcur[t] = excl; }
    if (t == NBUCKETS - 1) bbase[NBUCKETS] = excl + acc;  // = E
}

// Pass A: LDS multi-split into dst-buckets; ONE reserve-atomic per bucket
// per block. Packed entry = (src<<8) | (dst&255).
__global__ __launch_bounds__(256) void partA_kernel(
    const int* __restrict__ src, const int* __restrict__ dst,
    int* __restrict__ bcur, unsigned int* __restrict__ ebuf, int E) {
    __shared__ unsigned int stage[ACHUNK];       // 16 KB
    __shared__ unsigned short sb[ACHUNK];        // 8 KB
    __shared__ int hist[NB_PAD];
    __shared__ int ocnt[NB_PAD];
    __shared__ int gbase[NB_PAD];
    __shared__ int cnt2[NB_PAD];
    int t = threadIdx.x;
    int base = blockIdx.x * ACHUNK;
    int total = E - base; if (total > ACHUNK) total = ACHUNK;

    hist[t] = 0; hist[t + 256] = 0;
    cnt2[t] = 0; cnt2[t + 256] = 0;
    __syncthreads();

    unsigned int pe[16];
    unsigned short bk[16];
    #pragma unroll
    for (int k = 0; k < 16; ++k) {
        int e = base + k * 256 + t;
        if (e < E) {
            int s = src[e], d = dst[e];
            pe[k] = ((unsigned int)s << 8) | (unsigned int)(d & (BNODES - 1));
            bk[k] = (unsigned short)(d >> BSHIFT);
            atomicAdd(&hist[bk[k]], 1);
        } else {
            bk[k] = SENTB;
        }
    }
    __syncthreads();
    ocnt[t] = hist[t]; ocnt[t + 256] = hist[t + 256];
    __syncthreads();
    for (int off = 1; off < NB_PAD; off <<= 1) {
        int v0 = (t >= off) ? hist[t - off] : 0;
        int v1 = hist[t + 256 - off];
        __syncthreads();
        hist[t] += v0; hist[t + 256] += v1;
        __syncthreads();
    }
    #pragma unroll
    for (int i = 0; i < 2; ++i) {
        int b = (t + i * 256 + blockIdx.x * 131) & (NB_PAD - 1);
        int cc = ocnt[b];
        if (cc > 0 && b < NBUCKETS) gbase[b] = atomicAdd(&bcur[b], cc);
    }
    __syncthreads();
    #pragma unroll
    for (int k = 0; k < 16; ++k) {
        if (bk[k] != SENTB) {
            int b = bk[k];
            int pos = (hist[b] - ocnt[b]) + atomicAdd(&cnt2[b], 1);
            stage[pos] = pe[k];
            sb[pos] = (unsigned short)b;
        }
    }
    __syncthreads();
    #pragma unroll
    for (int k = 0; k < 16; ++k) {
        int idx = k * 256 + t;
        if (idx < total) {
            int b = sb[idx];
            int lo = hist[b] - ocnt[b];
            ebuf[gbase[b] + (idx - lo)] = stage[idx];
        }
    }
}

// Pass B: one block per bucket, in-place counting sort; ALSO emits
// row_ptr + dinv for its 256 nodes and the fp16 pre-scaled y rows.
__global__ __launch_bounds__(256) void partB_kernel(
    const int* __restrict__ bbase, unsigned int* __restrict__ csr,
    int* __restrict__ row_ptr, float* __restrict__ dinv,
    const float4* __restrict__ x4, __half2* __restrict__ y2,
    int n, int E, int do_y) {
    __shared__ int lcnt[BNODES];
    __shared__ int lscan[BNODES];
    __shared__ int lcur[BNODES];
    __shared__ float sdinv[BNODES];
    __shared__ unsigned int sbuf[BCAP];
    int b = blockIdx.x, t = threadIdx.x;
    int node0 = b << BSHIFT;
    int nlocal = min(BNODES, n - node0);
    int base = bbase[b];
    int endp = bbase[b + 1];
    int cnt = endp - base;
    lcnt[t] = 0;
    __syncthreads();
    unsigned int er[BCAP / 256];
    #pragma unroll
    for (int k = 0; k < BCAP / 256; ++k) {
        int idx = k * 256 + t;
        er[k] = (idx < cnt) ? csr[base + idx] : 0xFFFFFFFFu;
        if (er[k] != 0xFFFFFFFFu) atomicAdd(&lcnt[er[k] & (BNODES - 1)], 1);
    }
    __syncthreads();
    int own = lcnt[t];
    sdinv[t] = rsqrtf((float)own + 1.0f);
    lscan[t] = own;
    __syncthreads();
    for (int off = 1; off < BNODES; off <<= 1) {
        int v = (t >= off) ? lscan[t - off] : 0;
        __syncthreads();
        lscan[t] += v;
        __syncthreads();
    }
    int excl = lscan[t] - own;
    lcur[t] = excl;
    if (t < nlocal) {
        row_ptr[node0 + t] = base + excl;
        dinv[node0 + t] = sdinv[t];
    }
    if (t == 0 && node0 + nlocal == n) row_ptr[n] = E;
    __syncthreads();
    #pragma unroll
    for (int k = 0; k < BCAP / 256; ++k) {
        unsigned int e = er[k];
        if (e != 0xFFFFFFFFu) {
            int p = atomicAdd(&lcur[(int)(e & (BNODES - 1))], 1);
            sbuf[p] = e >> 8;
        }
    }
    __syncthreads();
    for (int idx = t; idx < cnt; idx += 256) csr[base + idx] = sbuf[idx];
    if (do_y) {
        for (int i = t; i < nlocal * 16; i += 256) {
            int nl = i >> 4;
            int gi = (node0 + nl) * 16 + (i & 15);
            float di = sdinv[nl];
            float4 xv = x4[gi];
            y2[2 * gi]     = __floats2half2_rn(xv.x * di, xv.y * di);
            y2[2 * gi + 1] = __floats2half2_rn(xv.z * di, xv.w * di);
        }
    }
}

// Fused layer 1: block = 4 waves = 16 nodes (one MFMA tile).
// Gather phase interleaves the wave's 4 nodes (up to 8 y-gathers in flight).
__global__ __launch_bounds__(256) void fused1_kernel(
    const uint4* __restrict__ y, const float4* __restrict__ x4,
    const int* __restrict__ row_ptr, const int* __restrict__ csr,
    const float* __restrict__ dinv, const uint4* __restrict__ Wpk,
    const float* __restrict__ b1, const float* __restrict__ v,
    float* __restrict__ zz, int n) {
    __shared__ uint4 Atile[16 * 9];
    int t = threadIdx.x;
    int lane = t & 63;
    int wave = t >> 6;
    int node0 = blockIdx.x * 16;
    int q = lane >> 3, col = lane & 7;

    if (y) {
        int nodew = node0 + wave * 4;
        int rp[5];
        #pragma unroll
        for (int m = 0; m < 5; ++m) rp[m] = row_ptr[nodew + m];
        float f[4][8];
        #pragma unroll
        for (int m = 0; m < 4; ++m)
            #pragma unroll
            for (int r = 0; r < 8; ++r) f[m][r] = 0.f;
        if (q == 0) {
            #pragma unroll
            for (int m = 0; m < 4; ++m) {
                uint4 su = y[(nodew + m) * 8 + col];
                accum8(f[m], su);
            }
        }
        int pos[4], s0[4], s1[4];
        #pragma unroll
        for (int m = 0; m < 4; ++m) {
            pos[m] = rp[m];
            int p = pos[m] + q;
            s0[m] = (p < rp[m + 1]) ? csr[p] : -1;
            s1[m] = (p + 8 < rp[m + 1]) ? csr[p + 8] : -1;
        }
        while (true) {
            uint4 u0[4], u1[4];
            #pragma unroll
            for (int m = 0; m < 4; ++m) if (s0[m] >= 0) u0[m] = y[s0[m] * 8 + col];
            #pragma unroll
            for (int m = 0; m < 4; ++m) if (s1[m] >= 0) u1[m] = y[s1[m] * 8 + col];
            int n0[4], n1[4];
            #pragma unroll
            for (int m = 0; m < 4; ++m) {
                int np = pos[m] + 16 + q;
                n0[m] = (np < rp[m + 1]) ? csr[np] : -1;
                n1[m] = (np + 8 < rp[m + 1]) ? csr[np + 8] : -1;
            }
            #pragma unroll
            for (int m = 0; m < 4; ++m) {
                if (s0[m] >= 0) accum8(f[m], u0[m]);
                if (s1[m] >= 0) accum8(f[m], u1[m]);
            }
            bool more = false;
            #pragma unroll
            for (int m = 0; m < 4; ++m) {
                pos[m] += 16;
                more |= (pos[m] < rp[m + 1]);
                s0[m] = n0[m]; s1[m] = n1[m];
            }
            if (!more) break;
        }
        #pragma unroll
        for (int m = 0; m < 4; ++m) {
            #pragma unroll
            for (int off = 8; off < 64; off <<= 1) {
                #pragma unroll
                for (int r = 0; r < 8; ++r) f[m][r] += __shfl_xor(f[m][r], off, 64);
            }
            if (lane < 8) {
                float di = dinv[nodew + m];
                union { uint4 u; __half2 h[4]; } pk;
                #pragma unroll
                for (int r = 0; r < 4; ++r)
                    pk.h[r] = __floats2half2_rn(di * f[m][2 * r], di * f[m][2 * r + 1]);
                Atile[(wave * 4 + m) * 9 + lane] = pk.u;
            }
        }
    } else {
        // f32 fallback: sequential per-node gather with per-src weight dinv[s]
        #pragma unroll
        for (int j = 0; j < 4; ++j) {
            int m = wave * 4 + j;
            int node = node0 + m;
            float f[8];
            #pragma unroll
            for (int r = 0; r < 8; ++r) f[r] = 0.f;
            int beg = row_ptr[node], end = row_ptr[node + 1];
            if (q == 0) {
                float di0 = dinv[node];
                float4 a = x4[node * 16 + 2 * col];
                float4 b = x4[node * 16 + 2 * col + 1];
                f[0] = di0 * a.x; f[1] = di0 * a.y; f[2] = di0 * a.z; f[3] = di0 * a.w;
                f[4] = di0 * b.x; f[5] = di0 * b.y; f[6] = di0 * b.z; f[7] = di0 * b.w;
            }
            int p = beg + q;
            int s0 = (p < end) ? csr[p] : -1;
            int s1 = (p + 8 < end) ? csr[p + 8] : -1;
            for (int cb = beg; cb < end; cb += 16) {
                int c0 = s0, c1 = s1;
                int np = cb + 16 + q;
                s0 = (np < end) ? csr[np] : -1;
                s1 = (np + 8 < end) ? csr[np + 8] : -1;
                if (c0 >= 0) {
                    float w = dinv[c0];
                    float4 a = x4[c0 * 16 + 2 * col];
                    float4 b = x4[c0 * 16 + 2 * col + 1];
                    f[0] += w * a.x; f[1] += w * a.y; f[2] += w * a.z; f[3] += w * a.w;
                    f[4] += w * b.x; f[5] += w * b.y; f[6] += w * b.z; f[7] += w * b.w;
                }
                if (c1 >= 0) {
                    float w = dinv[c1];
                    float4 a = x4[c1 * 16 + 2 * col];
                    float4 b = x4[c1 * 16 + 2 * col + 1];
                    f[0] += w * a.x; f[1] += w * a.y; f[2] += w * a.z; f[3] += w * a.w;
                    f[4] += w * b.x; f[5] += w * b.y; f[6] += w * b.z; f[7] += w * b.w;
                }
            }
            #pragma unroll
            for (int off = 8; off < 64; off <<= 1) {
                #pragma unroll
                for (int r = 0; r < 8; ++r) f[r] += __shfl_xor(f[r], off, 64);
            }
            if (lane < 8) {
                float di = dinv[node];
                union { uint4 u; __half2 h[4]; } pk;
                #pragma unroll
                for (int r = 0; r < 4; ++r)
                    pk.h[r] = __floats2half2_rn(di * f[2 * r], di * f[2 * r + 1]);
                Atile[m * 9 + lane] = pk.u;
            }
        }
    }
    __syncthreads();
    if (t >= 64) return;

    int mm = lane & 15, kq = lane >> 4;
    half8 A0 = as_half8(Atile[mm * 9 + kq]);
    half8 A1 = as_half8(Atile[mm * 9 + 4 + kq]);
    f32x4 acc[8];
    #pragma unroll
    for (int cb = 0; cb < 8; ++cb) acc[cb] = (f32x4){0.f, 0.f, 0.f, 0.f};
    #pragma unroll
    for (int cb = 0; cb < 8; ++cb) {
        half8 bh0 = as_half8(Wpk[(cb * 2 + 0) * 64 + lane]);
        half8 bh1 = as_half8(Wpk[(cb * 2 + 1) * 64 + lane]);
        half8 bl0 = as_half8(Wpk[1024 + (cb * 2 + 0) * 64 + lane]);
        half8 bl1 = as_half8(Wpk[1024 + (cb * 2 + 1) * 64 + lane]);
        acc[cb] = __builtin_amdgcn_mfma_f32_16x16x32_f16(A0, bh0, acc[cb], 0, 0, 0);
        acc[cb] = __builtin_amdgcn_mfma_f32_16x16x32_f16(A1, bh1, acc[cb], 0, 0, 0);
        acc[cb] = __builtin_amdgcn_mfma_f32_16x16x32_f16(A0, bl0, acc[cb], 0, 0, 0);
        acc[cb] = __builtin_amdgcn_mfma_f32_16x16x32_f16(A1, bl1, acc[cb], 0, 0, 0);
    }
    float zp[4] = {0.f, 0.f, 0.f, 0.f};
    #pragma unroll
    for (int cb = 0; cb < 8; ++cb) {
        int colg = cb * 16 + mm;
        float bb = b1[colg], vv = v[colg];
        #pragma unroll
        for (int r = 0; r < 4; ++r) {
            float h = acc[cb][r] + bb;
            h = fmaxf(h, 0.f);
            zp[r] += h * vv;
        }
    }
    #pragma unroll
    for (int off = 1; off < 16; off <<= 1) {
        #pragma unroll
        for (int r = 0; r < 4; ++r) zp[r] += __shfl_xor(zp[r], off, 64);
    }
    if (mm == 0) {
        int nb = node0 + kq * 4;
        #pragma unroll
        for (int r = 0; r < 4; ++r) zz[nb + r] = dinv[nb + r] * zp[r];
    }
}

// Layer 2 (collapsed): out[i] = c + dinv[i]*(zz[i] + sum_in zz[s]).
// 8 lanes/node, 2 pipelined slots per lane (csr prefetched a round ahead).
__global__ void out_kernel(const int* __restrict__ row_ptr, const int* __restrict__ csr,
                           const float* __restrict__ dinv, const float* __restrict__ zz,
                           const float* __restrict__ c, float* __restrict__ out, int n) {
    int tid = blockIdx.x * blockDim.x + threadIdx.x;
    int node = tid >> 3;
    int sub = tid & 7;
    if (node >= n) return;
    int beg = row_ptr[node], end = row_ptr[node + 1];
    float acc = 0.f;
    int p = beg + sub;
    int s0 = (p < end) ? csr[p] : -1;
    int s1 = (p + 8 < end) ? csr[p + 8] : -1;
    for (int cb = beg; cb < end; cb += 16) {
        int c0 = s0, c1 = s1;
        int np = cb + 16 + sub;
        s0 = (np < end) ? csr[np] : -1;
        s1 = (np + 8 < end) ? csr[np + 8] : -1;
        float z0 = (c0 >= 0) ? zz[c0] : 0.f;
        float z1 = (c1 >= 0) ? zz[c1] : 0.f;
        acc += z0 + z1;
    }
    acc += __shfl_xor(acc, 1, 64);
    acc += __shfl_xor(acc, 2, 64);
    acc += __shfl_xor(acc, 4, 64);
    if (sub == 0) out[node] = c[0] + dinv[node] * (acc + zz[node]);
}

extern "C" void kernel_launch(void* const* d_in, const int* in_sizes, int n_in,
                              void* d_out, int out_size, void* d_ws, size_t ws_size,
                              hipStream_t stream) {
    const float* x  = (const float*)d_in[0];
    const int*   ei = (const int*)d_in[1];
    const float* W1 = (const float*)d_in[2];
    const float* b1 = (const float*)d_in[3];
    const float* W2 = (const float*)d_in[4];
    const float* b2 = (const float*)d_in[5];
    const float* Wl = (const float*)d_in[6];
    const float* bl = (const float*)d_in[7];
    float* out = (float*)d_out;

    int E = in_sizes[1] / 2;
    const int* src = ei;
    const int* dst = ei + E;
    int Epad = (E + 3) & ~3;

    float* ws      = (float*)d_ws;
    float* dinv    = ws;                       // N
    int*   row_ptr = (int*)(ws + N_NODES);     // N+4
    float* zz      = (float*)(row_ptr + N_NODES + 4);  // N
    float* v       = zz + N_NODES;             // 128
    float* c       = v + HID;                  // 4
    int*   bbase   = (int*)(c + 4);            // 512
    int*   bcur    = bbase + 512;              // 512
    int*   gcnt    = bcur + 512;               // 512
    int*   csr     = gcnt + 512;               // Epad (bmat overlays)
    int*   bmat    = csr;                      // overlay: used only before partA
    uint4* Wpk     = (uint4*)(csr + Epad);     // 2048 uint4 (32 KB)
    __half* y      = (__half*)((float*)Wpk + 8192);  // N*64 halves

    size_t base_floats = (size_t)N_NODES * 3 + 4 + 128 + 4 + 1536 + (size_t)Epad + 8192;
    size_t need_f16 = (base_floats + (size_t)N_NODES * 32) * 4;
    bool use_f16 = (ws_size >= need_f16);

    int nchunks = (E + ACHUNK - 1) / ACHUNK;   // 391
    int nred = (nchunks + RROWS - 1) / RROWS;  // 25

    prep_hist_kernel<<<9 + nchunks, 256, 0, stream>>>(
        W1, W2, b2, Wl, bl, v, c, Wpk, gcnt, dst, bmat, E);
    breduce_kernel<<<nred, 256, 0, stream>>>(bmat, gcnt, nchunks);
    bscan_kernel<<<1, 512, 0, stream>>>(gcnt, bbase, bcur, E);
    partA_kernel<<<nchunks, 256, 0, stream>>>(src, dst, bcur, (unsigned int*)csr, E);
    partB_kernel<<<NBUCKETS, 256, 0, stream>>>(
        bbase, (unsigned int*)csr, row_ptr, dinv,
        (const float4*)x, (__half2*)y, N_NODES, E, use_f16 ? 1 : 0);
    fused1_kernel<<<N_NODES / 16, 256, 0, stream>>>(
        use_f16 ? (const uint4*)y : nullptr, (const float4*)x,
        row_ptr, csr, dinv, Wpk, b1, v, zz, N_NODES);
    out_kernel<<<(N_NODES * 8 + 255) / 256, 256, 0, stream>>>(
        row_ptr, csr, dinv, zz, c, out, N_NODES);
}

// Round 14
// 190.847 us; speedup vs baseline: 4.2369x; 1.0886x over previous
//
#include <hip/hip_runtime.h>
#include <hip/hip_fp16.h>

// GCN 2-layer, N=100000, F=64, H=128, O=100, out [N,1] fp32.
// out = agg(relu(agg(x)@W1 + b1) . (W2@Wl)) + (b2@Wl + bl)
// agg via CSR-by-dst GATHER; layer-1 GEMV via MFMA (fp16 hi+lo split W1).
// PADDED CSR: bucket b owns slots [b*SCAP, (b+1)*SCAP) — bases are static,
// so no counting pass. partA multi-splits edges in; partB counting-sorts
// in-bucket and emits per-node rs/re + dinv + fp16 y.

#define N_NODES 100000
#define F_IN 64
#define HID 128
#define OUT2 100
#define BSHIFT 8
#define BNODES 256
#define NBUCKETS ((N_NODES + BNODES - 1) / BNODES)  // 391
#define SCAP 4608   // bucket capacity: mean 4096 + 8 sigma (sigma=64)
#define ACHUNK 4096 // edges per partA block
#define NB_PAD 512
#define SENTB 0xFFFFu

typedef _Float16 half8 __attribute__((ext_vector_type(8)));
typedef float f32x4 __attribute__((ext_vector_type(4)));

static __device__ __forceinline__ half8 as_half8(uint4 u) {
    union { uint4 u; half8 h; } x; x.u = u; return x.h;
}

static __device__ __forceinline__ void accum8(float* f, uint4 u) {
    const __half2* hp = (const __half2*)&u;
    #pragma unroll
    for (int r = 0; r < 4; ++r) {
        float2 fv = __half22float2(hp[r]);
        f[2 * r] += fv.x; f[2 * r + 1] += fv.y;
    }
}

// Blocks 0..7: pack W1 (MFMA B-layout, fp16 hi+lo).
// Block 8: v = W2@Wl, c = b2.Wl + bl, init bcur[b] = b*SCAP.
__global__ __launch_bounds__(256) void prep_kernel(
    const float* __restrict__ W1, const float* __restrict__ W2,
    const float* __restrict__ b2, const float* __restrict__ Wl,
    const float* __restrict__ bl,
    float* __restrict__ v, float* __restrict__ c, uint4* __restrict__ Wpk,
    int* __restrict__ bcur) {
    int t = threadIdx.x;
    if (blockIdx.x < 8) {
        // idx: bit10 = part (0=hi,1=lo), bits9..7 = cb, bit6 = kf, bits5..0 = lane
        int idx = blockIdx.x * 256 + t;
        int lane2 = idx & 63;
        int kf    = (idx >> 6) & 1;
        int cb    = (idx >> 7) & 7;
        int part  = (idx >> 10) & 1;
        union { uint4 u; unsigned short s[8]; } pk;
        #pragma unroll
        for (int j = 0; j < 8; ++j) {
            int k    = kf * 32 + (lane2 >> 4) * 8 + j;
            int colg = cb * 16 + (lane2 & 15);
            float w = W1[k * HID + colg];
            __half h = __float2half_rn(w);
            if (part) h = __float2half_rn(w - __half2float(h));
            pk.s[j] = __half_as_ushort(h);
        }
        Wpk[idx] = pk.u;
    } else {
        bcur[t] = t * SCAP;
        bcur[t + 256] = (t + 256) * SCAP;
        if (t < HID) {
            float acc = 0.f;
            for (int k = 0; k < OUT2; ++k) acc += W2[t * OUT2 + k] * Wl[k];
            v[t] = acc;
        } else if (t == HID) {
            float acc = bl[0];
            for (int k = 0; k < OUT2; ++k) acc += b2[k] * Wl[k];
            *c = acc;
        }
    }
}

// Pass A: LDS multi-split into padded dst-buckets; ONE reserve-atomic per
// bucket per block. Packed entry = (src<<8) | (dst&255).
__global__ __launch_bounds__(256) void partA_kernel(
    const int* __restrict__ src, const int* __restrict__ dst,
    int* __restrict__ bcur, unsigned int* __restrict__ ebuf, int E) {
    __shared__ unsigned int stage[ACHUNK];       // 16 KB
    __shared__ unsigned short sb[ACHUNK];        // 8 KB
    __shared__ int hist[NB_PAD];
    __shared__ int ocnt[NB_PAD];
    __shared__ int gbase[NB_PAD];
    __shared__ int cnt2[NB_PAD];
    int t = threadIdx.x;
    int base = blockIdx.x * ACHUNK;
    int total = E - base; if (total > ACHUNK) total = ACHUNK;

    hist[t] = 0; hist[t + 256] = 0;
    cnt2[t] = 0; cnt2[t + 256] = 0;
    __syncthreads();

    unsigned int pe[16];
    unsigned short bk[16];
    #pragma unroll
    for (int k = 0; k < 16; ++k) {
        int e = base + k * 256 + t;
        if (e < E) {
            int s = src[e], d = dst[e];
            pe[k] = ((unsigned int)s << 8) | (unsigned int)(d & (BNODES - 1));
            bk[k] = (unsigned short)(d >> BSHIFT);
            atomicAdd(&hist[bk[k]], 1);
        } else {
            bk[k] = SENTB;
        }
    }
    __syncthreads();
    ocnt[t] = hist[t]; ocnt[t + 256] = hist[t + 256];
    __syncthreads();
    for (int off = 1; off < NB_PAD; off <<= 1) {
        int v0 = (t >= off) ? hist[t - off] : 0;
        int v1 = hist[t + 256 - off];
        __syncthreads();
        hist[t] += v0; hist[t + 256] += v1;
        __syncthreads();
    }
    #pragma unroll
    for (int i = 0; i < 2; ++i) {
        int b = (t + i * 256 + blockIdx.x * 131) & (NB_PAD - 1);
        int cc = ocnt[b];
        if (cc > 0 && b < NBUCKETS) gbase[b] = atomicAdd(&bcur[b], cc);
    }
    __syncthreads();
    #pragma unroll
    for (int k = 0; k < 16; ++k) {
        if (bk[k] != SENTB) {
            int b = bk[k];
            int pos = (hist[b] - ocnt[b]) + atomicAdd(&cnt2[b], 1);
            stage[pos] = pe[k];
            sb[pos] = (unsigned short)b;
        }
    }
    __syncthreads();
    #pragma unroll
    for (int k = 0; k < 16; ++k) {
        int idx = k * 256 + t;
        if (idx < total) {
            int b = sb[idx];
            int lo = hist[b] - ocnt[b];
            ebuf[gbase[b] + (idx - lo)] = stage[idx];
        }
    }
}

// Pass B: one block per bucket, in-place counting sort in [b*SCAP, b*SCAP+cnt);
// emits per-node rs/re + dinv + fp16 pre-scaled y rows.
__global__ __launch_bounds__(256) void partB_kernel(
    const int* __restrict__ bcur, unsigned int* __restrict__ csr,
    int* __restrict__ rs, int* __restrict__ re, float* __restrict__ dinv,
    const float4* __restrict__ x4, __half2* __restrict__ y2,
    int n, int do_y) {
    __shared__ int lcnt[BNODES];
    __shared__ int lscan[BNODES];
    __shared__ int lcur[BNODES];
    __shared__ float sdinv[BNODES];
    __shared__ unsigned int sbuf[SCAP];
    int b = blockIdx.x, t = threadIdx.x;
    int node0 = b << BSHIFT;
    int nlocal = min(BNODES, n - node0);
    int base = b * SCAP;
    int cnt = bcur[b] - base;
    lcnt[t] = 0;
    __syncthreads();
    unsigned int er[SCAP / 256];
    #pragma unroll
    for (int k = 0; k < SCAP / 256; ++k) {
        int idx = k * 256 + t;
        er[k] = (idx < cnt) ? csr[base + idx] : 0xFFFFFFFFu;
        if (er[k] != 0xFFFFFFFFu) atomicAdd(&lcnt[er[k] & (BNODES - 1)], 1);
    }
    __syncthreads();
    int own = lcnt[t];
    sdinv[t] = rsqrtf((float)own + 1.0f);
    lscan[t] = own;
    __syncthreads();
    for (int off = 1; off < BNODES; off <<= 1) {
        int v = (t >= off) ? lscan[t - off] : 0;
        __syncthreads();
        lscan[t] += v;
        __syncthreads();
    }
    int excl = lscan[t] - own;
    lcur[t] = excl;
    if (t < nlocal) {
        rs[node0 + t] = base + excl;
        re[node0 + t] = base + excl + own;
        dinv[node0 + t] = sdinv[t];
    }
    __syncthreads();
    #pragma unroll
    for (int k = 0; k < SCAP / 256; ++k) {
        unsigned int e = er[k];
        if (e != 0xFFFFFFFFu) {
            int p = atomicAdd(&lcur[(int)(e & (BNODES - 1))], 1);
            sbuf[p] = e >> 8;
        }
    }
    __syncthreads();
    for (int idx = t; idx < cnt; idx += 256) csr[base + idx] = sbuf[idx];
    if (do_y) {
        for (int i = t; i < nlocal * 16; i += 256) {
            int nl = i >> 4;
            int gi = (node0 + nl) * 16 + (i & 15);
            float di = sdinv[nl];
            float4 xv = x4[gi];
            y2[2 * gi]     = __floats2half2_rn(xv.x * di, xv.y * di);
            y2[2 * gi + 1] = __floats2half2_rn(xv.z * di, xv.w * di);
        }
    }
}

// Fused layer 1: block = 4 waves = 16 nodes (one MFMA tile).
// Gather phase interleaves the wave's 4 nodes (up to 8 y-gathers in flight).
__global__ __launch_bounds__(256) void fused1_kernel(
    const uint4* __restrict__ y, const float4* __restrict__ x4,
    const int* __restrict__ rs_, const int* __restrict__ re_,
    const int* __restrict__ csr,
    const float* __restrict__ dinv, const uint4* __restrict__ Wpk,
    const float* __restrict__ b1, const float* __restrict__ v,
    float* __restrict__ zz, int n) {
    __shared__ uint4 Atile[16 * 9];
    int t = threadIdx.x;
    int lane = t & 63;
    int wave = t >> 6;
    int node0 = blockIdx.x * 16;
    int q = lane >> 3, col = lane & 7;

    if (y) {
        int nodew = node0 + wave * 4;
        int rb[4], rend[4];
        #pragma unroll
        for (int m = 0; m < 4; ++m) { rb[m] = rs_[nodew + m]; rend[m] = re_[nodew + m]; }
        float f[4][8];
        #pragma unroll
        for (int m = 0; m < 4; ++m)
            #pragma unroll
            for (int r = 0; r < 8; ++r) f[m][r] = 0.f;
        if (q == 0) {
            #pragma unroll
            for (int m = 0; m < 4; ++m) {
                uint4 su = y[(nodew + m) * 8 + col];
                accum8(f[m], su);
            }
        }
        int pos[4], s0[4], s1[4];
        #pragma unroll
        for (int m = 0; m < 4; ++m) {
            pos[m] = rb[m];
            int p = pos[m] + q;
            s0[m] = (p < rend[m]) ? csr[p] : -1;
            s1[m] = (p + 8 < rend[m]) ? csr[p + 8] : -1;
        }
        while (true) {
            uint4 u0[4], u1[4];
            #pragma unroll
            for (int m = 0; m < 4; ++m) if (s0[m] >= 0) u0[m] = y[s0[m] * 8 + col];
            #pragma unroll
            for (int m = 0; m < 4; ++m) if (s1[m] >= 0) u1[m] = y[s1[m] * 8 + col];
            int n0[4], n1[4];
            #pragma unroll
            for (int m = 0; m < 4; ++m) {
                int np = pos[m] + 16 + q;
                n0[m] = (np < rend[m]) ? csr[np] : -1;
                n1[m] = (np + 8 < rend[m]) ? csr[np + 8] : -1;
            }
            #pragma unroll
            for (int m = 0; m < 4; ++m) {
                if (s0[m] >= 0) accum8(f[m], u0[m]);
                if (s1[m] >= 0) accum8(f[m], u1[m]);
            }
            bool more = false;
            #pragma unroll
            for (int m = 0; m < 4; ++m) {
                pos[m] += 16;
                more |= (pos[m] < rend[m]);
                s0[m] = n0[m]; s1[m] = n1[m];
            }
            if (!more) break;
        }
        #pragma unroll
        for (int m = 0; m < 4; ++m) {
            #pragma unroll
            for (int off = 8; off < 64; off <<= 1) {
                #pragma unroll
                for (int r = 0; r < 8; ++r) f[m][r] += __shfl_xor(f[m][r], off, 64);
            }
            if (lane < 8) {
                float di = dinv[nodew + m];
                union { uint4 u; __half2 h[4]; } pk;
                #pragma unroll
                for (int r = 0; r < 4; ++r)
                    pk.h[r] = __floats2half2_rn(di * f[m][2 * r], di * f[m][2 * r + 1]);
                Atile[(wave * 4 + m) * 9 + lane] = pk.u;
            }
        }
    } else {
        // f32 fallback: sequential per-node gather with per-src weight dinv[s]
        #pragma unroll
        for (int j = 0; j < 4; ++j) {
            int m = wave * 4 + j;
            int node = node0 + m;
            float f[8];
            #pragma unroll
            for (int r = 0; r < 8; ++r) f[r] = 0.f;
            int beg = rs_[node], end = re_[node];
            if (q == 0) {
                float di0 = dinv[node];
                float4 a = x4[node * 16 + 2 * col];
                float4 b = x4[node * 16 + 2 * col + 1];
                f[0] = di0 * a.x; f[1] = di0 * a.y; f[2] = di0 * a.z; f[3] = di0 * a.w;
                f[4] = di0 * b.x; f[5] = di0 * b.y; f[6] = di0 * b.z; f[7] = di0 * b.w;
            }
            int p = beg + q;
            int s0 = (p < end) ? csr[p] : -1;
            int s1 = (p + 8 < end) ? csr[p + 8] : -1;
            for (int cb = beg; cb < end; cb += 16) {
                int c0 = s0, c1 = s1;
                int np = cb + 16 + q;
                s0 = (np < end) ? csr[np] : -1;
                s1 = (np + 8 < end) ? csr[np + 8] : -1;
                if (c0 >= 0) {
                    float w = dinv[c0];
                    float4 a = x4[c0 * 16 + 2 * col];
                    float4 b = x4[c0 * 16 + 2 * col + 1];
                    f[0] += w * a.x; f[1] += w * a.y; f[2] += w * a.z; f[3] += w * a.w;
                    f[4] += w * b.x; f[5] += w * b.y; f[6] += w * b.z; f[7] += w * b.w;
                }
                if (c1 >= 0) {
                    float w = dinv[c1];
                    float4 a = x4[c1 * 16 + 2 * col];
                    float4 b = x4[c1 * 16 + 2 * col + 1];
                    f[0] += w * a.x; f[1] += w * a.y; f[2] += w * a.z; f[3] += w * a.w;
                    f[4] += w * b.x; f[5] += w * b.y; f[6] += w * b.z; f[7] += w * b.w;
                }
            }
            #pragma unroll
            for (int off = 8; off < 64; off <<= 1) {
                #pragma unroll
                for (int r = 0; r < 8; ++r) f[r] += __shfl_xor(f[r], off, 64);
            }
            if (lane < 8) {
                float di = dinv[node];
                union { uint4 u; __half2 h[4]; } pk;
                #pragma unroll
                for (int r = 0; r < 4; ++r)
                    pk.h[r] = __floats2half2_rn(di * f[2 * r], di * f[2 * r + 1]);
                Atile[m * 9 + lane] = pk.u;
            }
        }
    }
    __syncthreads();
    if (t >= 64) return;

    int mm = lane & 15, kq = lane >> 4;
    half8 A0 = as_half8(Atile[mm * 9 + kq]);
    half8 A1 = as_half8(Atile[mm * 9 + 4 + kq]);
    f32x4 acc[8];
    #pragma unroll
    for (int cb = 0; cb < 8; ++cb) acc[cb] = (f32x4){0.f, 0.f, 0.f, 0.f};
    #pragma unroll
    for (int cb = 0; cb < 8; ++cb) {
        half8 bh0 = as_half8(Wpk[(cb * 2 + 0) * 64 + lane]);
        half8 bh1 = as_half8(Wpk[(cb * 2 + 1) * 64 + lane]);
        half8 bl0 = as_half8(Wpk[1024 + (cb * 2 + 0) * 64 + lane]);
        half8 bl1 = as_half8(Wpk[1024 + (cb * 2 + 1) * 64 + lane]);
        acc[cb] = __builtin_amdgcn_mfma_f32_16x16x32_f16(A0, bh0, acc[cb], 0, 0, 0);
        acc[cb] = __builtin_amdgcn_mfma_f32_16x16x32_f16(A1, bh1, acc[cb], 0, 0, 0);
        acc[cb] = __builtin_amdgcn_mfma_f32_16x16x32_f16(A0, bl0, acc[cb], 0, 0, 0);
        acc[cb] = __builtin_amdgcn_mfma_f32_16x16x32_f16(A1, bl1, acc[cb], 0, 0, 0);
    }
    float zp[4] = {0.f, 0.f, 0.f, 0.f};
    #pragma unroll
    for (int cb = 0; cb < 8; ++cb) {
        int colg = cb * 16 + mm;
        float bb = b1[colg], vv = v[colg];
        #pragma unroll
        for (int r = 0; r < 4; ++r) {
            float h = acc[cb][r] + bb;
            h = fmaxf(h, 0.f);
            zp[r] += h * vv;
        }
    }
    #pragma unroll
    for (int off = 1; off < 16; off <<= 1) {
        #pragma unroll
        for (int r = 0; r < 4; ++r) zp[r] += __shfl_xor(zp[r], off, 64);
    }
    if (mm == 0) {
        int nb = node0 + kq * 4;
        #pragma unroll
        for (int r = 0; r < 4; ++r) zz[nb + r] = dinv[nb + r] * zp[r];
    }
}

// Layer 2 (collapsed): out[i] = c + dinv[i]*(zz[i] + sum_in zz[s]).
// 8 lanes/node, 2 pipelined slots per lane (csr prefetched a round ahead).
__global__ void out_kernel(const int* __restrict__ rs, const int* __restrict__ re,
                           const int* __restrict__ csr,
                           const float* __restrict__ dinv, const float* __restrict__ zz,
                           const float* __restrict__ c, float* __restrict__ out, int n) {
    int tid = blockIdx.x * blockDim.x + threadIdx.x;
    int node = tid >> 3;
    int sub = tid & 7;
    if (node >= n) return;
    int beg = rs[node], end = re[node];
    float acc = 0.f;
    int p = beg + sub;
    int s0 = (p < end) ? csr[p] : -1;
    int s1 = (p + 8 < end) ? csr[p + 8] : -1;
    for (int cb = beg; cb < end; cb += 16) {
        int c0 = s0, c1 = s1;
        int np = cb + 16 + sub;
        s0 = (np < end) ? csr[np] : -1;
        s1 = (np + 8 < end) ? csr[np + 8] : -1;
        float z0 = (c0 >= 0) ? zz[c0] : 0.f;
        float z1 = (c1 >= 0) ? zz[c1] : 0.f;
        acc += z0 + z1;
    }
    acc += __shfl_xor(acc, 1, 64);
    acc += __shfl_xor(acc, 2, 64);
    acc += __shfl_xor(acc, 4, 64);
    if (sub == 0) out[node] = c[0] + dinv[node] * (acc + zz[node]);
}

extern "C" void kernel_launch(void* const* d_in, const int* in_sizes, int n_in,
                              void* d_out, int out_size, void* d_ws, size_t ws_size,
                              hipStream_t stream) {
    const float* x  = (const float*)d_in[0];
    const int*   ei = (const int*)d_in[1];
    const float* W1 = (const float*)d_in[2];
    const float* b1 = (const float*)d_in[3];
    const float* W2 = (const float*)d_in[4];
    const float* b2 = (const float*)d_in[5];
    const float* Wl = (const float*)d_in[6];
    const float* bl = (const float*)d_in[7];
    float* out = (float*)d_out;

    int E = in_sizes[1] / 2;
    const int* src = ei;
    const int* dst = ei + E;

    float* ws      = (float*)d_ws;
    float* dinv    = ws;                        // N
    int*   rs      = (int*)(ws + N_NODES);      // N
    int*   re      = rs + N_NODES;              // N
    float* zz      = (float*)(re + N_NODES);    // N
    float* v       = zz + N_NODES;              // 128
    float* c       = v + HID;                   // 4
    int*   bcur    = (int*)(c + 4);             // 512
    int*   csr     = bcur + 512;                // NBUCKETS*SCAP
    uint4* Wpk     = (uint4*)(csr + (size_t)NBUCKETS * SCAP);  // 2048 uint4
    __half* y      = (__half*)((float*)Wpk + 8192);            // N*64 halves

    size_t base_floats = (size_t)N_NODES * 4 + 128 + 4 + 512
                       + (size_t)NBUCKETS * SCAP + 8192;
    size_t need_f16 = (base_floats + (size_t)N_NODES * 32) * 4;
    bool use_f16 = (ws_size >= need_f16);

    int nchunks = (E + ACHUNK - 1) / ACHUNK;   // 391

    prep_kernel<<<9, 256, 0, stream>>>(W1, W2, b2, Wl, bl, v, c, Wpk, bcur);
    partA_kernel<<<nchunks, 256, 0, stream>>>(src, dst, bcur, (unsigned int*)csr, E);
    partB_kernel<<<NBUCKETS, 256, 0, stream>>>(
        bcur, (unsigned int*)csr, rs, re, dinv,
        (const float4*)x, (__half2*)y, N_NODES, use_f16 ? 1 : 0);
    fused1_kernel<<<N_NODES / 16, 256, 0, stream>>>(
        use_f16 ? (const uint4*)y : nullptr, (const float4*)x,
        rs, re, csr, dinv, Wpk, b1, v, zz, N_NODES);
    out_kernel<<<(N_NODES * 8 + 255) / 256, 256, 0, stream>>>(
        rs, re, csr, dinv, zz, c, out, N_NODES);
}